// Round 1
// baseline (710.138 us; speedup 1.0000x reference)
//
#include <hip/hip_runtime.h>
#include <hip/hip_bf16.h>

#define NNODES 50000
#define NEDGES 800000
#define KHOP 3

// ---------------- degree histogram ----------------
__global__ void hist_kernel(const int* __restrict__ dst, int* __restrict__ cnt, int e) {
  int i = blockIdx.x * blockDim.x + threadIdx.x;
  if (i < e) atomicAdd(&cnt[dst[i]], 1);
}

__global__ void dis_kernel(const int* __restrict__ cnt, float* __restrict__ dis, int n) {
  int i = blockIdx.x * blockDim.x + threadIdx.x;
  if (i < n) {
    int c = cnt[i];
    dis[i] = (c > 0) ? rsqrtf((float)c) : 0.0f;
  }
}

// ---------------- exclusive scan (single block, chunked) ----------------
__global__ __launch_bounds__(1024) void scan_kernel(const int* __restrict__ cnt,
                                                    int* __restrict__ row_ptr,
                                                    int* __restrict__ cursor, int n) {
  __shared__ int sd[1024];
  int tid = threadIdx.x;
  const int chunk = (n + 1023) / 1024;
  int begI = tid * chunk;
  int endI = begI + chunk; if (endI > n) endI = n;
  int sum = 0;
  for (int i = begI; i < endI; ++i) sum += cnt[i];
  sd[tid] = sum;
  __syncthreads();
  for (int offd = 1; offd < 1024; offd <<= 1) {
    int t = (tid >= offd) ? sd[tid - offd] : 0;
    __syncthreads();
    sd[tid] += t;
    __syncthreads();
  }
  int run = sd[tid] - sum;  // exclusive prefix of this thread's chunk
  for (int i = begI; i < endI; ++i) {
    row_ptr[i] = run; cursor[i] = run; run += cnt[i];
  }
  if (tid == 1023) row_ptr[n] = sd[1023];
}

// ---------------- bucket edges into CSR ----------------
__global__ void scatter_kernel(const int* __restrict__ src, const int* __restrict__ dst,
                               const float* __restrict__ dis, int* __restrict__ cursor,
                               int* __restrict__ csr_src, float* __restrict__ csr_nrm, int e) {
  int i = blockIdx.x * blockDim.x + threadIdx.x;
  if (i < e) {
    int s = src[i], d = dst[i];
    int pos = atomicAdd(&cursor[d], 1);
    csr_src[pos] = s;
    csr_nrm[pos] = dis[s] * dis[d];
  }
}

// ---------------- repack W2 [512,40] -> W2p [128,160] ----------------
__global__ void w2p_kernel(const float* __restrict__ W2, float* __restrict__ W2p) {
  int t = blockIdx.x * blockDim.x + threadIdx.x;
  if (t < 128 * 160) {
    int r = t / 160, q = t - r * 160;
    int k = q / 40, c = q - k * 40;
    W2p[t] = W2[(size_t)(k * 128 + r) * 40 + c];
  }
}

// ---------------- copy x into P block 0 ([N,512] col 0..127) ----------------
__global__ void copyx_kernel(const float* __restrict__ x, float* __restrict__ P, int n) {
  int t = blockIdx.x * blockDim.x + threadIdx.x;
  int i = t >> 5;
  int c = (t & 31) << 2;
  if (i < n) *(float4*)&P[(size_t)i * 512 + c] = *(const float4*)&x[(size_t)i * 128 + c];
}

// ---------------- 128-dim propagation: out = A_hat * in (wave per node) ----------------
__global__ __launch_bounds__(256) void prop128_kernel(
    const float* __restrict__ in, float* __restrict__ out,
    const int* __restrict__ row_ptr, const int* __restrict__ csr_src,
    const float* __restrict__ csr_nrm, int n) {
  int node = (int)((blockIdx.x * blockDim.x + threadIdx.x) >> 6);
  int lane = threadIdx.x & 63;
  if (node >= n) return;
  int beg = row_ptr[node], end = row_ptr[node + 1];
  float ax = 0.f, ay = 0.f;
  int j = beg;
  for (; j + 2 <= end; j += 2) {
    int s0 = csr_src[j], s1 = csr_src[j + 1];
    float w0 = csr_nrm[j], w1 = csr_nrm[j + 1];
    float2 v0 = *(const float2*)&in[(size_t)s0 * 512 + 2 * lane];
    float2 v1 = *(const float2*)&in[(size_t)s1 * 512 + 2 * lane];
    ax = fmaf(w0, v0.x, ax); ay = fmaf(w0, v0.y, ay);
    ax = fmaf(w1, v1.x, ax); ay = fmaf(w1, v1.y, ay);
  }
  if (j < end) {
    int s0 = csr_src[j]; float w0 = csr_nrm[j];
    float2 v0 = *(const float2*)&in[(size_t)s0 * 512 + 2 * lane];
    ax = fmaf(w0, v0.x, ax); ay = fmaf(w0, v0.y, ay);
  }
  float2 o; o.x = ax; o.y = ay;
  *(float2*)&out[(size_t)node * 512 + 2 * lane] = o;
}

// ---------------- 40-dim propagation with additive term ----------------
__global__ __launch_bounds__(256) void prop40_kernel(
    const float* __restrict__ in, int in_stride,
    const float* __restrict__ add, int add_stride,
    float* __restrict__ out,
    const int* __restrict__ row_ptr, const int* __restrict__ csr_src,
    const float* __restrict__ csr_nrm, int n) {
  int node = (int)((blockIdx.x * blockDim.x + threadIdx.x) >> 6);
  int lane = threadIdx.x & 63;
  if (node >= n || lane >= 40) return;
  float acc = add[(size_t)node * add_stride + lane];
  int beg = row_ptr[node], end = row_ptr[node + 1];
  int j = beg;
  for (; j + 2 <= end; j += 2) {
    int s0 = csr_src[j], s1 = csr_src[j + 1];
    float w0 = csr_nrm[j], w1 = csr_nrm[j + 1];
    float v0 = in[(size_t)s0 * in_stride + lane];
    float v1 = in[(size_t)s1 * in_stride + lane];
    acc = fmaf(w0, v0, acc);
    acc = fmaf(w1, v1, acc);
  }
  if (j < end) acc = fmaf(csr_nrm[j], in[(size_t)csr_src[j] * in_stride + lane], acc);
  out[(size_t)node * 40 + lane] = acc;
}

// ---------------- GEMM1: H = relu(P[N,512] @ W1[512,128] + b1) ----------------
__global__ __launch_bounds__(256) void gemm1_kernel(
    const float* __restrict__ A, const float* __restrict__ W,
    const float* __restrict__ bias, float* __restrict__ C, int n) {
  __shared__ float As[64][32];
  __shared__ float Bs[32][128];
  const int tid = threadIdx.x;
  const int row0 = blockIdx.x * 64;
  const int tc = tid & 31;
  const int tr = tid >> 5;
  float acc[8][4];
#pragma unroll
  for (int r = 0; r < 8; ++r) { acc[r][0] = acc[r][1] = acc[r][2] = acc[r][3] = 0.f; }
  for (int k0 = 0; k0 < 512; k0 += 32) {
    {
      int idx = tid * 8;
      int r = idx >> 5, c = idx & 31;
      int gr = row0 + r;
      float4 v0 = make_float4(0, 0, 0, 0), v1 = make_float4(0, 0, 0, 0);
      if (gr < n) {
        v0 = *(const float4*)&A[(size_t)gr * 512 + k0 + c];
        v1 = *(const float4*)&A[(size_t)gr * 512 + k0 + c + 4];
      }
      *(float4*)&As[r][c] = v0;
      *(float4*)&As[r][c + 4] = v1;
    }
#pragma unroll
    for (int t = 0; t < 4; ++t) {
      int idx = (t * 256 + tid) * 4;
      int r = idx >> 7, c = idx & 127;
      *(float4*)&Bs[r][c] = *(const float4*)&W[(size_t)(k0 + r) * 128 + c];
    }
    __syncthreads();
#pragma unroll
    for (int kk = 0; kk < 32; ++kk) {
      float a[8];
#pragma unroll
      for (int r = 0; r < 8; ++r) a[r] = As[tr * 8 + r][kk];
      float4 bv = *(const float4*)&Bs[kk][tc * 4];
#pragma unroll
      for (int r = 0; r < 8; ++r) {
        acc[r][0] = fmaf(a[r], bv.x, acc[r][0]);
        acc[r][1] = fmaf(a[r], bv.y, acc[r][1]);
        acc[r][2] = fmaf(a[r], bv.z, acc[r][2]);
        acc[r][3] = fmaf(a[r], bv.w, acc[r][3]);
      }
    }
    __syncthreads();
  }
  float4 bv = *(const float4*)&bias[tc * 4];
#pragma unroll
  for (int r = 0; r < 8; ++r) {
    int gr = row0 + tr * 8 + r;
    if (gr < n) {
      float4 o;
      o.x = fmaxf(acc[r][0] + bv.x, 0.f);
      o.y = fmaxf(acc[r][1] + bv.y, 0.f);
      o.z = fmaxf(acc[r][2] + bv.z, 0.f);
      o.w = fmaxf(acc[r][3] + bv.w, 0.f);
      *(float4*)&C[(size_t)gr * 128 + tc * 4] = o;
    }
  }
}

// ---------------- GEMM2: G = H[N,128] @ W2p[128,160] ----------------
__global__ __launch_bounds__(256) void gemm2_kernel(
    const float* __restrict__ A, const float* __restrict__ W,
    float* __restrict__ C, int n) {
  __shared__ float As[64][32];
  __shared__ float Bs[32][160];
  const int tid = threadIdx.x;
  const int row0 = blockIdx.x * 64;
  const int tc = tid & 31;
  const int tr = tid >> 5;
  float acc[8][5];
#pragma unroll
  for (int r = 0; r < 8; ++r)
#pragma unroll
    for (int c = 0; c < 5; ++c) acc[r][c] = 0.f;
  for (int k0 = 0; k0 < 128; k0 += 32) {
    {
      int idx = tid * 8;
      int r = idx >> 5, c = idx & 31;
      int gr = row0 + r;
      float4 v0 = make_float4(0, 0, 0, 0), v1 = make_float4(0, 0, 0, 0);
      if (gr < n) {
        v0 = *(const float4*)&A[(size_t)gr * 128 + k0 + c];
        v1 = *(const float4*)&A[(size_t)gr * 128 + k0 + c + 4];
      }
      *(float4*)&As[r][c] = v0;
      *(float4*)&As[r][c + 4] = v1;
    }
    {
      int r = tid >> 3;
      int cb = (tid & 7) * 20;
#pragma unroll
      for (int t = 0; t < 5; ++t)
        *(float4*)&Bs[r][cb + 4 * t] = *(const float4*)&W[(size_t)(k0 + r) * 160 + cb + 4 * t];
    }
    __syncthreads();
#pragma unroll
    for (int kk = 0; kk < 32; ++kk) {
      float a[8];
#pragma unroll
      for (int r = 0; r < 8; ++r) a[r] = As[tr * 8 + r][kk];
      float b[5];
#pragma unroll
      for (int c = 0; c < 5; ++c) b[c] = Bs[kk][tc * 5 + c];
#pragma unroll
      for (int r = 0; r < 8; ++r)
#pragma unroll
        for (int c = 0; c < 5; ++c) acc[r][c] = fmaf(a[r], b[c], acc[r][c]);
    }
    __syncthreads();
  }
#pragma unroll
  for (int r = 0; r < 8; ++r) {
    int gr = row0 + tr * 8 + r;
    if (gr < n) {
#pragma unroll
      for (int c = 0; c < 5; ++c) C[(size_t)gr * 160 + tc * 5 + c] = acc[r][c];
    }
  }
}

// ---------------- log_softmax over 40 cols (wave per node) ----------------
__global__ __launch_bounds__(256) void lsm_kernel(const float* __restrict__ t,
                                                  const float* __restrict__ b2,
                                                  float* __restrict__ out, int n) {
  int node = (int)((blockIdx.x * blockDim.x + threadIdx.x) >> 6);
  int lane = threadIdx.x & 63;
  if (node >= n) return;
  float v = (lane < 40) ? t[(size_t)node * 40 + lane] + b2[lane] : -__builtin_inff();
  float m = v;
#pragma unroll
  for (int offd = 32; offd; offd >>= 1) m = fmaxf(m, __shfl_xor(m, offd, 64));
  float p = (lane < 40) ? expf(v - m) : 0.f;
  float s = p;
#pragma unroll
  for (int offd = 32; offd; offd >>= 1) s += __shfl_xor(s, offd, 64);
  if (lane < 40) out[(size_t)node * 40 + lane] = v - m - logf(s);
}

extern "C" void kernel_launch(void* const* d_in, const int* in_sizes, int n_in,
                              void* d_out, int out_size, void* d_ws, size_t ws_size,
                              hipStream_t stream) {
  const float* x  = (const float*)d_in[0];
  const int*   ei = (const int*)d_in[1];
  const float* W1 = (const float*)d_in[2];
  const float* b1 = (const float*)d_in[3];
  const float* W2 = (const float*)d_in[4];
  const float* b2 = (const float*)d_in[5];
  const int* srcv = ei;
  const int* dstv = ei + NEDGES;
  float* out = (float*)d_out;

  char* wsb = (char*)d_ws;
  size_t off = 0;
  auto alloc = [&](size_t bytes) {
    char* p = wsb + off;
    off += (bytes + 255) & ~(size_t)255;
    return p;
  };
  int*   cnt     = (int*)  alloc((size_t)NNODES * 4);
  float* dis     = (float*)alloc((size_t)NNODES * 4);
  int*   row_ptr = (int*)  alloc(((size_t)NNODES + 1) * 4);
  int*   cursor  = (int*)  alloc((size_t)NNODES * 4);
  int*   csr_src = (int*)  alloc((size_t)NEDGES * 4);
  float* csr_nrm = (float*)alloc((size_t)NEDGES * 4);
  float* W2p     = (float*)alloc((size_t)128 * 160 * 4);
  float* H       = (float*)alloc((size_t)NNODES * 128 * 4);
  float* P       = (float*)alloc((size_t)NNODES * 512 * 4);
  // After GEMM1, P is dead: reuse its space for G [N,160] and t/t2 [N,40].
  float* G  = P;
  float* tb = P + (size_t)NNODES * 160;
  float* t2 = tb + (size_t)NNODES * 40;

  hipMemsetAsync(cnt, 0, (size_t)NNODES * 4, stream);
  hist_kernel<<<(NEDGES + 255) / 256, 256, 0, stream>>>(dstv, cnt, NEDGES);
  dis_kernel<<<(NNODES + 255) / 256, 256, 0, stream>>>(cnt, dis, NNODES);
  scan_kernel<<<1, 1024, 0, stream>>>(cnt, row_ptr, cursor, NNODES);
  scatter_kernel<<<(NEDGES + 255) / 256, 256, 0, stream>>>(srcv, dstv, dis, cursor,
                                                           csr_src, csr_nrm, NEDGES);
  w2p_kernel<<<(128 * 160 + 255) / 256, 256, 0, stream>>>(W2, W2p);
  copyx_kernel<<<((NNODES * 32) + 255) / 256, 256, 0, stream>>>(x, P, NNODES);

  const int prop_blocks = (NNODES * 64 + 255) / 256;
  // Layer 1: P blocks k = A_hat^k x
  for (int k = 1; k <= KHOP; ++k)
    prop128_kernel<<<prop_blocks, 256, 0, stream>>>(P + 128 * (k - 1), P + 128 * k,
                                                    row_ptr, csr_src, csr_nrm, NNODES);
  gemm1_kernel<<<(NNODES + 63) / 64, 256, 0, stream>>>(P, W1, b1, H, NNODES);
  gemm2_kernel<<<(NNODES + 63) / 64, 256, 0, stream>>>(H, W2p, G, NNODES);
  // Horner: t = A*G3 + G2 ; t2 = A*t + G1 ; t = A*t2 + G0
  prop40_kernel<<<prop_blocks, 256, 0, stream>>>(G + 120, 160, G + 80, 160, tb,
                                                 row_ptr, csr_src, csr_nrm, NNODES);
  prop40_kernel<<<prop_blocks, 256, 0, stream>>>(tb, 40, G + 40, 160, t2,
                                                 row_ptr, csr_src, csr_nrm, NNODES);
  prop40_kernel<<<prop_blocks, 256, 0, stream>>>(t2, 40, G + 0, 160, tb,
                                                 row_ptr, csr_src, csr_nrm, NNODES);
  lsm_kernel<<<prop_blocks, 256, 0, stream>>>(tb, b2, out, NNODES);
}

// Round 2
// 544.914 us; speedup vs baseline: 1.3032x; 1.3032x over previous
//
#include <hip/hip_runtime.h>
#include <hip/hip_bf16.h>

#define NNODES 50000
#define NROWP  50176   // padded row count (multiple of 64) for GEMM tiles
#define NEDGES 800000
#define KHOP 3

typedef __attribute__((ext_vector_type(8))) short short8v;
typedef __attribute__((ext_vector_type(8))) __bf16 bf16x8;
typedef __attribute__((ext_vector_type(4))) float f32x4;

__device__ inline unsigned short f2bf(float f) {
  unsigned u = __builtin_bit_cast(unsigned, f);
  u += 0x7fffu + ((u >> 16) & 1u);   // RNE
  return (unsigned short)(u >> 16);
}
__device__ inline float bflo(unsigned u) { return __builtin_bit_cast(float, u << 16); }
__device__ inline float bfhi(unsigned u) { return __builtin_bit_cast(float, u & 0xffff0000u); }

__device__ inline void gload_lds16(const void* g, void* l) {
  __builtin_amdgcn_global_load_lds(
      (const __attribute__((address_space(1))) unsigned int*)g,
      (__attribute__((address_space(3))) unsigned int*)l, 16, 0, 0);
}

__device__ inline f32x4 mfma_bf16(bf16x8 a, bf16x8 b, f32x4 c) {
  return __builtin_amdgcn_mfma_f32_16x16x32_bf16(a, b, c, 0, 0, 0);
}

// ---------------- CSR build ----------------
__global__ void hist_kernel(const int* __restrict__ dst, int* __restrict__ cnt, int e) {
  int i = blockIdx.x * blockDim.x + threadIdx.x;
  if (i < e) atomicAdd(&cnt[dst[i]], 1);
}

__global__ void dis_kernel(const int* __restrict__ cnt, float* __restrict__ dis, int n) {
  int i = blockIdx.x * blockDim.x + threadIdx.x;
  if (i < n) {
    int c = cnt[i];
    dis[i] = (c > 0) ? rsqrtf((float)c) : 0.0f;
  }
}

__global__ __launch_bounds__(1024) void scan_kernel(const int* __restrict__ cnt,
                                                    int* __restrict__ row_ptr,
                                                    int* __restrict__ cursor, int n) {
  __shared__ int sd[1024];
  int tid = threadIdx.x;
  const int chunk = (n + 1023) / 1024;
  int begI = tid * chunk;
  int endI = begI + chunk; if (endI > n) endI = n;
  int sum = 0;
  for (int i = begI; i < endI; ++i) sum += cnt[i];
  sd[tid] = sum;
  __syncthreads();
  for (int offd = 1; offd < 1024; offd <<= 1) {
    int t = (tid >= offd) ? sd[tid - offd] : 0;
    __syncthreads();
    sd[tid] += t;
    __syncthreads();
  }
  int run = sd[tid] - sum;
  for (int i = begI; i < endI; ++i) {
    row_ptr[i] = run; cursor[i] = run; run += cnt[i];
  }
  if (tid == 1023) row_ptr[n] = sd[1023];
}

__global__ void scatter_kernel(const int* __restrict__ src, const int* __restrict__ dst,
                               const float* __restrict__ dis, int* __restrict__ cursor,
                               int* __restrict__ csr_src, float* __restrict__ csr_nrm, int e) {
  int i = blockIdx.x * blockDim.x + threadIdx.x;
  if (i < e) {
    int s = src[i], d = dst[i];
    int pos = atomicAdd(&cursor[d], 1);
    csr_src[pos] = s;
    csr_nrm[pos] = dis[s] * dis[d];
  }
}

// ---------------- weight transforms ----------------
// W1t[c][k] = bf16(W1[k][c]);  [128][512]
__global__ void w1t_kernel(const float* __restrict__ W1, unsigned short* __restrict__ W1t) {
  int t = blockIdx.x * blockDim.x + threadIdx.x;
  if (t < 512 * 128) {
    int c = t >> 9, k = t & 511;
    W1t[t] = f2bf(W1[(size_t)k * 128 + c]);
  }
}

// W2pt[q][r] = bf16(W2[(k*128+r)*40 + c]), q = k*40+c;  [160][128]
__global__ void w2pt_kernel(const float* __restrict__ W2, unsigned short* __restrict__ W2pt) {
  int t = blockIdx.x * blockDim.x + threadIdx.x;
  if (t < 160 * 128) {
    int q = t >> 7, r = t & 127;
    int k = q / 40, c = q - k * 40;
    W2pt[t] = f2bf(W2[(size_t)(k * 128 + r) * 40 + c]);
  }
}

// ---------------- x -> bf16 into P block 0 ----------------
__global__ void copyx_kernel(const float* __restrict__ x, unsigned short* __restrict__ P, int n) {
  int t = blockIdx.x * blockDim.x + threadIdx.x;
  int i = t >> 5;
  int c4 = (t & 31) << 2;
  if (i < n) {
    float4 v = *(const float4*)&x[(size_t)i * 128 + c4];
    unsigned lo = (unsigned)f2bf(v.x) | ((unsigned)f2bf(v.y) << 16);
    unsigned hi = (unsigned)f2bf(v.z) | ((unsigned)f2bf(v.w) << 16);
    uint2 o; o.x = lo; o.y = hi;
    *(uint2*)&P[(size_t)i * 512 + c4] = o;
  }
}

// ---------------- 128-dim bf16 propagation (wave per node) ----------------
__global__ __launch_bounds__(256) void prop128b_kernel(
    const unsigned short* __restrict__ in, unsigned short* __restrict__ out,
    const int* __restrict__ row_ptr, const int* __restrict__ csr_src,
    const float* __restrict__ csr_nrm, int n) {
  int node = (int)((blockIdx.x * blockDim.x + threadIdx.x) >> 6);
  int lane = threadIdx.x & 63;
  if (node >= n) return;
  int beg = row_ptr[node], end = row_ptr[node + 1];
  float ax = 0.f, ay = 0.f;
  int j = beg;
  for (; j + 2 <= end; j += 2) {
    int s0 = csr_src[j], s1 = csr_src[j + 1];
    float w0 = csr_nrm[j], w1 = csr_nrm[j + 1];
    unsigned p0 = *(const unsigned*)&in[(size_t)s0 * 512 + 2 * lane];
    unsigned p1 = *(const unsigned*)&in[(size_t)s1 * 512 + 2 * lane];
    ax = fmaf(w0, bflo(p0), ax); ay = fmaf(w0, bfhi(p0), ay);
    ax = fmaf(w1, bflo(p1), ax); ay = fmaf(w1, bfhi(p1), ay);
  }
  if (j < end) {
    int s0 = csr_src[j]; float w0 = csr_nrm[j];
    unsigned p0 = *(const unsigned*)&in[(size_t)s0 * 512 + 2 * lane];
    ax = fmaf(w0, bflo(p0), ax); ay = fmaf(w0, bfhi(p0), ay);
  }
  unsigned o = (unsigned)f2bf(ax) | ((unsigned)f2bf(ay) << 16);
  *(unsigned*)&out[(size_t)node * 512 + 2 * lane] = o;
}

// ---------------- GEMM1 (MFMA): H = relu(P[N,512] @ W1 + b1), bf16 out ----------------
// block: 64 rows x 128 cols, 4 waves (2 row-halves x 2 col-halves)
__global__ __launch_bounds__(256) void gemm1m_kernel(
    const unsigned short* __restrict__ A,    // [NROWP][512] bf16
    const unsigned short* __restrict__ Bt,   // [128][512] bf16 (W1 transposed)
    const float* __restrict__ bias,
    unsigned short* __restrict__ H) {        // [NROWP][128] bf16
  __shared__ short As[64 * 32];
  __shared__ short Bs[128 * 32];
  const int tid = threadIdx.x;
  const int lane = tid & 63;
  const int w = tid >> 6;
  const int wr = w & 1;
  const int wc = w >> 1;
  const int row0 = blockIdx.x * 64;
  f32x4 acc[2][4];
#pragma unroll
  for (int i = 0; i < 2; ++i)
#pragma unroll
    for (int j = 0; j < 4; ++j) acc[i][j] = (f32x4)0.f;

  const int lrow = lane >> 2;  // 0..15
  const int lkp = lane & 3;    // 16B chunk within 64B row-slice

  for (int k0 = 0; k0 < 512; k0 += 32) {
    gload_lds16(A + (size_t)(row0 + w * 16 + lrow) * 512 + k0 + lkp * 8, &As[w * 512]);
    gload_lds16(Bt + (size_t)(w * 16 + lrow) * 512 + k0 + lkp * 8, &Bs[w * 512]);
    gload_lds16(Bt + (size_t)((w + 4) * 16 + lrow) * 512 + k0 + lkp * 8, &Bs[(w + 4) * 512]);
    __syncthreads();
    const int kg = lane >> 4, rr = lane & 15;
    bf16x8 af[2], bfr[4];
#pragma unroll
    for (int mr = 0; mr < 2; ++mr)
      af[mr] = __builtin_bit_cast(bf16x8,
          *(const short8v*)&As[(wr * 32 + mr * 16 + rr) * 32 + kg * 8]);
#pragma unroll
    for (int nr = 0; nr < 4; ++nr)
      bfr[nr] = __builtin_bit_cast(bf16x8,
          *(const short8v*)&Bs[(wc * 64 + nr * 16 + rr) * 32 + kg * 8]);
#pragma unroll
    for (int mr = 0; mr < 2; ++mr)
#pragma unroll
      for (int nr = 0; nr < 4; ++nr)
        acc[mr][nr] = mfma_bf16(af[mr], bfr[nr], acc[mr][nr]);
    __syncthreads();
  }
  const int cg = lane >> 4, cl = lane & 15;
#pragma unroll
  for (int mr = 0; mr < 2; ++mr)
#pragma unroll
    for (int nr = 0; nr < 4; ++nr) {
      int col = wc * 64 + nr * 16 + cl;
      float bv = bias[col];
#pragma unroll
      for (int j = 0; j < 4; ++j) {
        int row = row0 + wr * 32 + mr * 16 + cg * 4 + j;
        H[(size_t)row * 128 + col] = f2bf(fmaxf(acc[mr][nr][j] + bv, 0.f));
      }
    }
}

// ---------------- GEMM2 (MFMA): G = H[N,128] @ W2p -> fp32 [N,160] ----------------
// block: 64 rows x 160 cols, 4 waves split by row (16 rows each)
__global__ __launch_bounds__(256) void gemm2m_kernel(
    const unsigned short* __restrict__ A,    // [NROWP][128] bf16
    const unsigned short* __restrict__ Bt,   // [160][128] bf16
    float* __restrict__ G) {                 // [NROWP][160] f32
  __shared__ short As[64 * 32];
  __shared__ short Bs[160 * 32];
  const int tid = threadIdx.x;
  const int lane = tid & 63;
  const int w = tid >> 6;
  const int row0 = blockIdx.x * 64;
  f32x4 acc[10];
#pragma unroll
  for (int i = 0; i < 10; ++i) acc[i] = (f32x4)0.f;
  const int lrow = lane >> 2, lkp = lane & 3;

  for (int k0 = 0; k0 < 128; k0 += 32) {
    gload_lds16(A + (size_t)(row0 + w * 16 + lrow) * 128 + k0 + lkp * 8, &As[w * 512]);
    for (int c = w; c < 10; c += 4)
      gload_lds16(Bt + (size_t)(c * 16 + lrow) * 128 + k0 + lkp * 8, &Bs[c * 512]);
    __syncthreads();
    const int kg = lane >> 4, rr = lane & 15;
    bf16x8 af = __builtin_bit_cast(bf16x8,
        *(const short8v*)&As[(w * 16 + rr) * 32 + kg * 8]);
#pragma unroll
    for (int nr = 0; nr < 10; ++nr) {
      bf16x8 bfr = __builtin_bit_cast(bf16x8,
          *(const short8v*)&Bs[(nr * 16 + rr) * 32 + kg * 8]);
      acc[nr] = mfma_bf16(af, bfr, acc[nr]);
    }
    __syncthreads();
  }
  const int cg = lane >> 4, cl = lane & 15;
#pragma unroll
  for (int nr = 0; nr < 10; ++nr) {
    int col = nr * 16 + cl;
#pragma unroll
    for (int j = 0; j < 4; ++j) {
      int row = row0 + w * 16 + cg * 4 + j;
      G[(size_t)row * 160 + col] = acc[nr][j];
    }
  }
}

// ---------------- 40-dim fp32 propagation with additive term ----------------
__global__ __launch_bounds__(256) void prop40_kernel(
    const float* __restrict__ in, int in_stride,
    const float* __restrict__ add, int add_stride,
    float* __restrict__ out,
    const int* __restrict__ row_ptr, const int* __restrict__ csr_src,
    const float* __restrict__ csr_nrm, int n) {
  int node = (int)((blockIdx.x * blockDim.x + threadIdx.x) >> 6);
  int lane = threadIdx.x & 63;
  if (node >= n || lane >= 40) return;
  float acc = add[(size_t)node * add_stride + lane];
  int beg = row_ptr[node], end = row_ptr[node + 1];
  int j = beg;
  for (; j + 2 <= end; j += 2) {
    int s0 = csr_src[j], s1 = csr_src[j + 1];
    float w0 = csr_nrm[j], w1 = csr_nrm[j + 1];
    float v0 = in[(size_t)s0 * in_stride + lane];
    float v1 = in[(size_t)s1 * in_stride + lane];
    acc = fmaf(w0, v0, acc);
    acc = fmaf(w1, v1, acc);
  }
  if (j < end) acc = fmaf(csr_nrm[j], in[(size_t)csr_src[j] * in_stride + lane], acc);
  out[(size_t)node * 40 + lane] = acc;
}

// ---------------- log_softmax over 40 cols (wave per node) ----------------
__global__ __launch_bounds__(256) void lsm_kernel(const float* __restrict__ t,
                                                  const float* __restrict__ b2,
                                                  float* __restrict__ out, int n) {
  int node = (int)((blockIdx.x * blockDim.x + threadIdx.x) >> 6);
  int lane = threadIdx.x & 63;
  if (node >= n) return;
  float v = (lane < 40) ? t[(size_t)node * 40 + lane] + b2[lane] : -__builtin_inff();
  float m = v;
#pragma unroll
  for (int offd = 32; offd; offd >>= 1) m = fmaxf(m, __shfl_xor(m, offd, 64));
  float p = (lane < 40) ? expf(v - m) : 0.f;
  float s = p;
#pragma unroll
  for (int offd = 32; offd; offd >>= 1) s += __shfl_xor(s, offd, 64);
  if (lane < 40) out[(size_t)node * 40 + lane] = v - m - logf(s);
}

extern "C" void kernel_launch(void* const* d_in, const int* in_sizes, int n_in,
                              void* d_out, int out_size, void* d_ws, size_t ws_size,
                              hipStream_t stream) {
  const float* x  = (const float*)d_in[0];
  const int*   ei = (const int*)d_in[1];
  const float* W1 = (const float*)d_in[2];
  const float* b1 = (const float*)d_in[3];
  const float* W2 = (const float*)d_in[4];
  const float* b2 = (const float*)d_in[5];
  const int* srcv = ei;
  const int* dstv = ei + NEDGES;
  float* out = (float*)d_out;

  char* wsb = (char*)d_ws;
  size_t off = 0;
  auto alloc = [&](size_t bytes) {
    char* p = wsb + off;
    off += (bytes + 255) & ~(size_t)255;
    return p;
  };
  int*            cnt     = (int*)            alloc((size_t)NNODES * 4);
  float*          dis     = (float*)          alloc((size_t)NNODES * 4);
  int*            row_ptr = (int*)            alloc(((size_t)NNODES + 1) * 4);
  int*            cursor  = (int*)            alloc((size_t)NNODES * 4);
  int*            csr_src = (int*)            alloc((size_t)NEDGES * 4);
  float*          csr_nrm = (float*)          alloc((size_t)NEDGES * 4);
  unsigned short* W1t     = (unsigned short*) alloc((size_t)128 * 512 * 2);
  unsigned short* W2pt    = (unsigned short*) alloc((size_t)160 * 128 * 2);
  unsigned short* P       = (unsigned short*) alloc((size_t)NROWP * 512 * 2);
  unsigned short* H       = (unsigned short*) alloc((size_t)NROWP * 128 * 2);
  float*          G       = (float*)          alloc((size_t)NROWP * 160 * 4);
  float*          tb      = (float*)          alloc((size_t)NNODES * 40 * 4);
  float*          t2      = (float*)          alloc((size_t)NNODES * 40 * 4);

  hipMemsetAsync(cnt, 0, (size_t)NNODES * 4, stream);
  hist_kernel<<<(NEDGES + 255) / 256, 256, 0, stream>>>(dstv, cnt, NEDGES);
  dis_kernel<<<(NNODES + 255) / 256, 256, 0, stream>>>(cnt, dis, NNODES);
  scan_kernel<<<1, 1024, 0, stream>>>(cnt, row_ptr, cursor, NNODES);
  scatter_kernel<<<(NEDGES + 255) / 256, 256, 0, stream>>>(srcv, dstv, dis, cursor,
                                                           csr_src, csr_nrm, NEDGES);
  w1t_kernel<<<(512 * 128 + 255) / 256, 256, 0, stream>>>(W1, W1t);
  w2pt_kernel<<<(160 * 128 + 255) / 256, 256, 0, stream>>>(W2, W2pt);
  copyx_kernel<<<((NNODES * 32) + 255) / 256, 256, 0, stream>>>(x, P, NNODES);

  const int prop_blocks = (NNODES * 64 + 255) / 256;
  // Layer 1: P blocks k = A_hat^k x  (bf16, row stride 512)
  for (int k = 1; k <= KHOP; ++k)
    prop128b_kernel<<<prop_blocks, 256, 0, stream>>>(P + 128 * (k - 1), P + 128 * k,
                                                     row_ptr, csr_src, csr_nrm, NNODES);
  const int gemm_blocks = (NNODES + 63) / 64;  // 782; rows < NROWP
  gemm1m_kernel<<<gemm_blocks, 256, 0, stream>>>(P, W1t, b1, H);
  gemm2m_kernel<<<gemm_blocks, 256, 0, stream>>>(H, W2pt, G);
  // Horner (fp32): tb = A*G3 + G2 ; t2 = A*tb + G1 ; tb = A*t2 + G0
  prop40_kernel<<<prop_blocks, 256, 0, stream>>>(G + 120, 160, G + 80, 160, tb,
                                                 row_ptr, csr_src, csr_nrm, NNODES);
  prop40_kernel<<<prop_blocks, 256, 0, stream>>>(tb, 40, G + 40, 160, t2,
                                                 row_ptr, csr_src, csr_nrm, NNODES);
  prop40_kernel<<<prop_blocks, 256, 0, stream>>>(t2, 40, G + 0, 160, tb,
                                                 row_ptr, csr_src, csr_nrm, NNODES);
  lsm_kernel<<<prop_blocks, 256, 0, stream>>>(tb, b2, out, NNODES);
}

// Round 3
// 444.859 us; speedup vs baseline: 1.5963x; 1.2249x over previous
//
#include <hip/hip_runtime.h>
#include <hip/hip_bf16.h>

#define NNODES 50000
#define NROWP  50176   // padded row count (multiple of 64) for GEMM tiles
#define NEDGES 800000
#define KHOP 3
#define SCAN_NB 49     // ceil(NNODES / 1024)

typedef __attribute__((ext_vector_type(8))) short short8v;
typedef __attribute__((ext_vector_type(8))) __bf16 bf16x8;
typedef __attribute__((ext_vector_type(4))) float f32x4;

__device__ inline unsigned short f2bf(float f) {
  unsigned u = __builtin_bit_cast(unsigned, f);
  u += 0x7fffu + ((u >> 16) & 1u);   // RNE
  return (unsigned short)(u >> 16);
}
__device__ inline float bflo(unsigned u) { return __builtin_bit_cast(float, u << 16); }
__device__ inline float bfhi(unsigned u) { return __builtin_bit_cast(float, u & 0xffff0000u); }

__device__ inline void gload_lds16(const void* g, void* l) {
  __builtin_amdgcn_global_load_lds(
      (const __attribute__((address_space(1))) unsigned int*)g,
      (__attribute__((address_space(3))) unsigned int*)l, 16, 0, 0);
}

__device__ inline f32x4 mfma_bf16(bf16x8 a, bf16x8 b, f32x4 c) {
  return __builtin_amdgcn_mfma_f32_16x16x32_bf16(a, b, c, 0, 0, 0);
}

// ---------------- CSR build ----------------
__global__ void hist_kernel(const int* __restrict__ dst, int* __restrict__ cnt, int e) {
  int i = blockIdx.x * blockDim.x + threadIdx.x;
  if (i < e) atomicAdd(&cnt[dst[i]], 1);
}

__global__ void dis_kernel(const int* __restrict__ cnt, float* __restrict__ dis, int n) {
  int i = blockIdx.x * blockDim.x + threadIdx.x;
  if (i < n) {
    int c = cnt[i];
    dis[i] = (c > 0) ? rsqrtf((float)c) : 0.0f;
  }
}

// --- hierarchical exclusive scan: bsum -> bscan -> bfinal ---
__global__ __launch_bounds__(256) void bsum_kernel(const int* __restrict__ cnt,
                                                   int* __restrict__ bsums, int n) {
  __shared__ int sd[256];
  int tid = threadIdx.x;
  int base = blockIdx.x * 1024 + tid * 4;
  int s = 0;
  if (base + 4 <= n) {
    int4 v = *(const int4*)&cnt[base];
    s = v.x + v.y + v.z + v.w;
  }
  sd[tid] = s;
  __syncthreads();
  for (int o = 128; o; o >>= 1) {
    if (tid < o) sd[tid] += sd[tid + o];
    __syncthreads();
  }
  if (tid == 0) bsums[blockIdx.x] = sd[0];
}

__global__ __launch_bounds__(64) void bscan_kernel(const int* __restrict__ bsums,
                                                   int* __restrict__ boff,
                                                   int* __restrict__ row_ptr,
                                                   int nb, int n) {
  int tid = threadIdx.x;
  int own = (tid < nb) ? bsums[tid] : 0;
  int v = own;
#pragma unroll
  for (int o = 1; o < 64; o <<= 1) {
    int t = __shfl_up(v, o, 64);
    if (tid >= o) v += t;
  }
  if (tid < nb) boff[tid] = v - own;   // exclusive block offset
  if (tid == 63) row_ptr[n] = v;       // total edge count
}

__global__ __launch_bounds__(256) void bfinal_kernel(const int* __restrict__ cnt,
                                                     const int* __restrict__ boff,
                                                     int* __restrict__ row_ptr,
                                                     int* __restrict__ cursor, int n) {
  __shared__ int sd[256];
  int tid = threadIdx.x;
  int base = blockIdx.x * 1024 + tid * 4;
  int4 v = make_int4(0, 0, 0, 0);
  bool ok = (base + 4 <= n);
  if (ok) v = *(const int4*)&cnt[base];
  int s = v.x + v.y + v.z + v.w;
  sd[tid] = s;
  __syncthreads();
  for (int o = 1; o < 256; o <<= 1) {
    int t = (tid >= o) ? sd[tid - o] : 0;
    __syncthreads();
    sd[tid] += t;
    __syncthreads();
  }
  if (ok) {
    int run = boff[blockIdx.x] + sd[tid] - s;  // exclusive prefix
    int4 rp;
    rp.x = run;
    rp.y = run + v.x;
    rp.z = rp.y + v.y;
    rp.w = rp.z + v.z;
    *(int4*)&row_ptr[base] = rp;
    *(int4*)&cursor[base] = rp;
  }
}

__global__ void scatter_kernel(const int* __restrict__ src, const int* __restrict__ dst,
                               const float* __restrict__ dis, int* __restrict__ cursor,
                               int* __restrict__ csr_src, float* __restrict__ csr_nrm, int e) {
  int i = blockIdx.x * blockDim.x + threadIdx.x;
  if (i < e) {
    int s = src[i], d = dst[i];
    int pos = atomicAdd(&cursor[d], 1);
    csr_src[pos] = s;
    csr_nrm[pos] = dis[s] * dis[d];
  }
}

// ---------------- weight transforms ----------------
// W1t[c][k] = bf16(W1[k][c]);  [128][512]
__global__ void w1t_kernel(const float* __restrict__ W1, unsigned short* __restrict__ W1t) {
  int t = blockIdx.x * blockDim.x + threadIdx.x;
  if (t < 512 * 128) {
    int c = t >> 9, k = t & 511;
    W1t[t] = f2bf(W1[(size_t)k * 128 + c]);
  }
}

// W2pt[q][r] = bf16(W2[(k*128+r)*40 + c]), q = k*40+c;  [160][128]
__global__ void w2pt_kernel(const float* __restrict__ W2, unsigned short* __restrict__ W2pt) {
  int t = blockIdx.x * blockDim.x + threadIdx.x;
  if (t < 160 * 128) {
    int q = t >> 7, r = t & 127;
    int k = q / 40, c = q - k * 40;
    W2pt[t] = f2bf(W2[(size_t)(k * 128 + r) * 40 + c]);
  }
}

// ---------------- x -> bf16 into P block 0 ----------------
__global__ void copyx_kernel(const float* __restrict__ x, unsigned short* __restrict__ P, int n) {
  int t = blockIdx.x * blockDim.x + threadIdx.x;
  int i = t >> 5;
  int c4 = (t & 31) << 2;
  if (i < n) {
    float4 v = *(const float4*)&x[(size_t)i * 128 + c4];
    unsigned lo = (unsigned)f2bf(v.x) | ((unsigned)f2bf(v.y) << 16);
    unsigned hi = (unsigned)f2bf(v.z) | ((unsigned)f2bf(v.w) << 16);
    uint2 o; o.x = lo; o.y = hi;
    *(uint2*)&P[(size_t)i * 512 + c4] = o;
  }
}

// ---------------- 128-dim bf16 propagation (wave per node) ----------------
__global__ __launch_bounds__(256) void prop128b_kernel(
    const unsigned short* __restrict__ in, unsigned short* __restrict__ out,
    const int* __restrict__ row_ptr, const int* __restrict__ csr_src,
    const float* __restrict__ csr_nrm, int n) {
  int node = (int)((blockIdx.x * blockDim.x + threadIdx.x) >> 6);
  int lane = threadIdx.x & 63;
  if (node >= n) return;
  int beg = row_ptr[node], end = row_ptr[node + 1];
  float ax = 0.f, ay = 0.f;
  int j = beg;
  for (; j + 2 <= end; j += 2) {
    int s0 = csr_src[j], s1 = csr_src[j + 1];
    float w0 = csr_nrm[j], w1 = csr_nrm[j + 1];
    unsigned p0 = *(const unsigned*)&in[(size_t)s0 * 512 + 2 * lane];
    unsigned p1 = *(const unsigned*)&in[(size_t)s1 * 512 + 2 * lane];
    ax = fmaf(w0, bflo(p0), ax); ay = fmaf(w0, bfhi(p0), ay);
    ax = fmaf(w1, bflo(p1), ax); ay = fmaf(w1, bfhi(p1), ay);
  }
  if (j < end) {
    int s0 = csr_src[j]; float w0 = csr_nrm[j];
    unsigned p0 = *(const unsigned*)&in[(size_t)s0 * 512 + 2 * lane];
    ax = fmaf(w0, bflo(p0), ax); ay = fmaf(w0, bfhi(p0), ay);
  }
  unsigned o = (unsigned)f2bf(ax) | ((unsigned)f2bf(ay) << 16);
  *(unsigned*)&out[(size_t)node * 512 + 2 * lane] = o;
}

// ---------------- GEMM1 (MFMA): H = relu(P[N,512] @ W1 + b1), bf16 out ----------------
// block: 64 rows x 128 cols, 4 waves (2 row-halves x 2 col-halves)
__global__ __launch_bounds__(256) void gemm1m_kernel(
    const unsigned short* __restrict__ A,    // [NROWP][512] bf16
    const unsigned short* __restrict__ Bt,   // [128][512] bf16 (W1 transposed)
    const float* __restrict__ bias,
    unsigned short* __restrict__ H) {        // [NROWP][128] bf16
  __shared__ short As[64 * 32];
  __shared__ short Bs[128 * 32];
  const int tid = threadIdx.x;
  const int lane = tid & 63;
  const int w = tid >> 6;
  const int wr = w & 1;
  const int wc = w >> 1;
  const int row0 = blockIdx.x * 64;
  f32x4 acc[2][4];
#pragma unroll
  for (int i = 0; i < 2; ++i)
#pragma unroll
    for (int j = 0; j < 4; ++j) acc[i][j] = (f32x4)0.f;

  const int lrow = lane >> 2;  // 0..15
  const int lkp = lane & 3;    // 16B chunk within 64B row-slice

  for (int k0 = 0; k0 < 512; k0 += 32) {
    gload_lds16(A + (size_t)(row0 + w * 16 + lrow) * 512 + k0 + lkp * 8, &As[w * 512]);
    gload_lds16(Bt + (size_t)(w * 16 + lrow) * 512 + k0 + lkp * 8, &Bs[w * 512]);
    gload_lds16(Bt + (size_t)((w + 4) * 16 + lrow) * 512 + k0 + lkp * 8, &Bs[(w + 4) * 512]);
    __syncthreads();
    const int kg = lane >> 4, rr = lane & 15;
    bf16x8 af[2], bfr[4];
#pragma unroll
    for (int mr = 0; mr < 2; ++mr)
      af[mr] = __builtin_bit_cast(bf16x8,
          *(const short8v*)&As[(wr * 32 + mr * 16 + rr) * 32 + kg * 8]);
#pragma unroll
    for (int nr = 0; nr < 4; ++nr)
      bfr[nr] = __builtin_bit_cast(bf16x8,
          *(const short8v*)&Bs[(wc * 64 + nr * 16 + rr) * 32 + kg * 8]);
#pragma unroll
    for (int mr = 0; mr < 2; ++mr)
#pragma unroll
      for (int nr = 0; nr < 4; ++nr)
        acc[mr][nr] = mfma_bf16(af[mr], bfr[nr], acc[mr][nr]);
    __syncthreads();
  }
  const int cg = lane >> 4, cl = lane & 15;
#pragma unroll
  for (int mr = 0; mr < 2; ++mr)
#pragma unroll
    for (int nr = 0; nr < 4; ++nr) {
      int col = wc * 64 + nr * 16 + cl;
      float bv = bias[col];
#pragma unroll
      for (int j = 0; j < 4; ++j) {
        int row = row0 + wr * 32 + mr * 16 + cg * 4 + j;
        H[(size_t)row * 128 + col] = f2bf(fmaxf(acc[mr][nr][j] + bv, 0.f));
      }
    }
}

// ---------------- GEMM2 (MFMA): G = H[N,128] @ W2p -> fp32 [N,160] ----------------
// block: 64 rows x 160 cols, 4 waves split by row (16 rows each)
__global__ __launch_bounds__(256) void gemm2m_kernel(
    const unsigned short* __restrict__ A,    // [NROWP][128] bf16
    const unsigned short* __restrict__ Bt,   // [160][128] bf16
    float* __restrict__ G) {                 // [NROWP][160] f32
  __shared__ short As[64 * 32];
  __shared__ short Bs[160 * 32];
  const int tid = threadIdx.x;
  const int lane = tid & 63;
  const int w = tid >> 6;
  const int row0 = blockIdx.x * 64;
  f32x4 acc[10];
#pragma unroll
  for (int i = 0; i < 10; ++i) acc[i] = (f32x4)0.f;
  const int lrow = lane >> 2, lkp = lane & 3;

  for (int k0 = 0; k0 < 128; k0 += 32) {
    gload_lds16(A + (size_t)(row0 + w * 16 + lrow) * 128 + k0 + lkp * 8, &As[w * 512]);
    for (int c = w; c < 10; c += 4)
      gload_lds16(Bt + (size_t)(c * 16 + lrow) * 128 + k0 + lkp * 8, &Bs[c * 512]);
    __syncthreads();
    const int kg = lane >> 4, rr = lane & 15;
    bf16x8 af = __builtin_bit_cast(bf16x8,
        *(const short8v*)&As[(w * 16 + rr) * 32 + kg * 8]);
#pragma unroll
    for (int nr = 0; nr < 10; ++nr) {
      bf16x8 bfr = __builtin_bit_cast(bf16x8,
          *(const short8v*)&Bs[(nr * 16 + rr) * 32 + kg * 8]);
      acc[nr] = mfma_bf16(af, bfr, acc[nr]);
    }
    __syncthreads();
  }
  const int cg = lane >> 4, cl = lane & 15;
#pragma unroll
  for (int nr = 0; nr < 10; ++nr) {
    int col = nr * 16 + cl;
#pragma unroll
    for (int j = 0; j < 4; ++j) {
      int row = row0 + w * 16 + cg * 4 + j;
      G[(size_t)row * 160 + col] = acc[nr][j];
    }
  }
}

// ---------------- 40-dim fp32 propagation with additive term ----------------
__global__ __launch_bounds__(256) void prop40_kernel(
    const float* __restrict__ in, int in_stride,
    const float* __restrict__ add, int add_stride,
    float* __restrict__ out,
    const int* __restrict__ row_ptr, const int* __restrict__ csr_src,
    const float* __restrict__ csr_nrm, int n) {
  int node = (int)((blockIdx.x * blockDim.x + threadIdx.x) >> 6);
  int lane = threadIdx.x & 63;
  if (node >= n || lane >= 40) return;
  float acc = add[(size_t)node * add_stride + lane];
  int beg = row_ptr[node], end = row_ptr[node + 1];
  int j = beg;
  for (; j + 2 <= end; j += 2) {
    int s0 = csr_src[j], s1 = csr_src[j + 1];
    float w0 = csr_nrm[j], w1 = csr_nrm[j + 1];
    float v0 = in[(size_t)s0 * in_stride + lane];
    float v1 = in[(size_t)s1 * in_stride + lane];
    acc = fmaf(w0, v0, acc);
    acc = fmaf(w1, v1, acc);
  }
  if (j < end) acc = fmaf(csr_nrm[j], in[(size_t)csr_src[j] * in_stride + lane], acc);
  out[(size_t)node * 40 + lane] = acc;
}

// ---------------- log_softmax over 40 cols (wave per node) ----------------
__global__ __launch_bounds__(256) void lsm_kernel(const float* __restrict__ t,
                                                  const float* __restrict__ b2,
                                                  float* __restrict__ out, int n) {
  int node = (int)((blockIdx.x * blockDim.x + threadIdx.x) >> 6);
  int lane = threadIdx.x & 63;
  if (node >= n) return;
  float v = (lane < 40) ? t[(size_t)node * 40 + lane] + b2[lane] : -__builtin_inff();
  float m = v;
#pragma unroll
  for (int offd = 32; offd; offd >>= 1) m = fmaxf(m, __shfl_xor(m, offd, 64));
  float p = (lane < 40) ? expf(v - m) : 0.f;
  float s = p;
#pragma unroll
  for (int offd = 32; offd; offd >>= 1) s += __shfl_xor(s, offd, 64);
  if (lane < 40) out[(size_t)node * 40 + lane] = v - m - logf(s);
}

extern "C" void kernel_launch(void* const* d_in, const int* in_sizes, int n_in,
                              void* d_out, int out_size, void* d_ws, size_t ws_size,
                              hipStream_t stream) {
  const float* x  = (const float*)d_in[0];
  const int*   ei = (const int*)d_in[1];
  const float* W1 = (const float*)d_in[2];
  const float* b1 = (const float*)d_in[3];
  const float* W2 = (const float*)d_in[4];
  const float* b2 = (const float*)d_in[5];
  const int* srcv = ei;
  const int* dstv = ei + NEDGES;
  float* out = (float*)d_out;

  char* wsb = (char*)d_ws;
  size_t off = 0;
  auto alloc = [&](size_t bytes) {
    char* p = wsb + off;
    off += (bytes + 255) & ~(size_t)255;
    return p;
  };
  int*            cnt     = (int*)            alloc((size_t)NNODES * 4);
  float*          dis     = (float*)          alloc((size_t)NNODES * 4);
  int*            row_ptr = (int*)            alloc(((size_t)NNODES + 1) * 4);
  int*            cursor  = (int*)            alloc((size_t)NNODES * 4);
  int*            bsums   = (int*)            alloc((size_t)SCAN_NB * 4);
  int*            boff    = (int*)            alloc((size_t)SCAN_NB * 4);
  int*            csr_src = (int*)            alloc((size_t)NEDGES * 4);
  float*          csr_nrm = (float*)          alloc((size_t)NEDGES * 4);
  unsigned short* W1t     = (unsigned short*) alloc((size_t)128 * 512 * 2);
  unsigned short* W2pt    = (unsigned short*) alloc((size_t)160 * 128 * 2);
  unsigned short* P       = (unsigned short*) alloc((size_t)NROWP * 512 * 2);
  unsigned short* H       = (unsigned short*) alloc((size_t)NROWP * 128 * 2);
  float*          G       = (float*)          alloc((size_t)NROWP * 160 * 4);
  float*          tb      = (float*)          alloc((size_t)NNODES * 40 * 4);
  float*          t2      = (float*)          alloc((size_t)NNODES * 40 * 4);

  hipMemsetAsync(cnt, 0, (size_t)NNODES * 4, stream);
  hist_kernel<<<(NEDGES + 255) / 256, 256, 0, stream>>>(dstv, cnt, NEDGES);
  dis_kernel<<<(NNODES + 255) / 256, 256, 0, stream>>>(cnt, dis, NNODES);
  bsum_kernel<<<SCAN_NB, 256, 0, stream>>>(cnt, bsums, NNODES);
  bscan_kernel<<<1, 64, 0, stream>>>(bsums, boff, row_ptr, SCAN_NB, NNODES);
  bfinal_kernel<<<SCAN_NB, 256, 0, stream>>>(cnt, boff, row_ptr, cursor, NNODES);
  scatter_kernel<<<(NEDGES + 255) / 256, 256, 0, stream>>>(srcv, dstv, dis, cursor,
                                                           csr_src, csr_nrm, NEDGES);
  w1t_kernel<<<(512 * 128 + 255) / 256, 256, 0, stream>>>(W1, W1t);
  w2pt_kernel<<<(160 * 128 + 255) / 256, 256, 0, stream>>>(W2, W2pt);
  copyx_kernel<<<((NNODES * 32) + 255) / 256, 256, 0, stream>>>(x, P, NNODES);

  const int prop_blocks = (NNODES * 64 + 255) / 256;
  // Layer 1: P blocks k = A_hat^k x  (bf16, row stride 512)
  for (int k = 1; k <= KHOP; ++k)
    prop128b_kernel<<<prop_blocks, 256, 0, stream>>>(P + 128 * (k - 1), P + 128 * k,
                                                     row_ptr, csr_src, csr_nrm, NNODES);
  const int gemm_blocks = (NNODES + 63) / 64;  // 784; rows < NROWP
  gemm1m_kernel<<<gemm_blocks, 256, 0, stream>>>(P, W1t, b1, H);
  gemm2m_kernel<<<gemm_blocks, 256, 0, stream>>>(H, W2pt, G);
  // Horner (fp32): tb = A*G3 + G2 ; t2 = A*tb + G1 ; tb = A*t2 + G0
  prop40_kernel<<<prop_blocks, 256, 0, stream>>>(G + 120, 160, G + 80, 160, tb,
                                                 row_ptr, csr_src, csr_nrm, NNODES);
  prop40_kernel<<<prop_blocks, 256, 0, stream>>>(tb, 40, G + 40, 160, t2,
                                                 row_ptr, csr_src, csr_nrm, NNODES);
  prop40_kernel<<<prop_blocks, 256, 0, stream>>>(t2, 40, G + 0, 160, tb,
                                                 row_ptr, csr_src, csr_nrm, NNODES);
  lsm_kernel<<<prop_blocks, 256, 0, stream>>>(tb, b2, out, NNODES);
}

// Round 4
// 405.278 us; speedup vs baseline: 1.7522x; 1.0977x over previous
//
#include <hip/hip_runtime.h>
#include <hip/hip_bf16.h>

#define NNODES 50000
#define NROWP  50176   // padded row count (multiple of 64) for GEMM tiles
#define NEDGES 800000
#define KHOP 3
#define SCAN_NB 49     // ceil(NNODES / 1024)

typedef __attribute__((ext_vector_type(8))) short short8v;
typedef __attribute__((ext_vector_type(8))) __bf16 bf16x8;
typedef __attribute__((ext_vector_type(4))) float f32x4;

__device__ inline unsigned short f2bf(float f) {
  unsigned u = __builtin_bit_cast(unsigned, f);
  u += 0x7fffu + ((u >> 16) & 1u);   // RNE
  return (unsigned short)(u >> 16);
}
__device__ inline float bf2f(unsigned short h) {
  return __builtin_bit_cast(float, (unsigned)h << 16);
}
__device__ inline float bflo(unsigned u) { return __builtin_bit_cast(float, u << 16); }
__device__ inline float bfhi(unsigned u) { return __builtin_bit_cast(float, u & 0xffff0000u); }

__device__ inline void gload_lds16(const void* g, void* l) {
  __builtin_amdgcn_global_load_lds(
      (const __attribute__((address_space(1))) unsigned int*)g,
      (__attribute__((address_space(3))) unsigned int*)l, 16, 0, 0);
}

__device__ inline f32x4 mfma_bf16(bf16x8 a, bf16x8 b, f32x4 c) {
  return __builtin_amdgcn_mfma_f32_16x16x32_bf16(a, b, c, 0, 0, 0);
}

// ---------------- CSR build ----------------
__global__ void hist_kernel(const int* __restrict__ dst, int* __restrict__ cnt, int e) {
  int i = blockIdx.x * blockDim.x + threadIdx.x;
  if (i < e) atomicAdd(&cnt[dst[i]], 1);
}

// --- hierarchical exclusive scan: bsum -> bscan -> bfinal (+dis fused) ---
__global__ __launch_bounds__(256) void bsum_kernel(const int* __restrict__ cnt,
                                                   int* __restrict__ bsums, int n) {
  __shared__ int sd[256];
  int tid = threadIdx.x;
  int base = blockIdx.x * 1024 + tid * 4;
  int s = 0;
  if (base + 4 <= n) {
    int4 v = *(const int4*)&cnt[base];
    s = v.x + v.y + v.z + v.w;
  }
  sd[tid] = s;
  __syncthreads();
  for (int o = 128; o; o >>= 1) {
    if (tid < o) sd[tid] += sd[tid + o];
    __syncthreads();
  }
  if (tid == 0) bsums[blockIdx.x] = sd[0];
}

__global__ __launch_bounds__(64) void bscan_kernel(const int* __restrict__ bsums,
                                                   int* __restrict__ boff,
                                                   int* __restrict__ row_ptr,
                                                   int nb, int n) {
  int tid = threadIdx.x;
  int own = (tid < nb) ? bsums[tid] : 0;
  int v = own;
#pragma unroll
  for (int o = 1; o < 64; o <<= 1) {
    int t = __shfl_up(v, o, 64);
    if (tid >= o) v += t;
  }
  if (tid < nb) boff[tid] = v - own;   // exclusive block offset
  if (tid == 63) row_ptr[n] = v;       // total edge count
}

__global__ __launch_bounds__(256) void bfinal_kernel(const int* __restrict__ cnt,
                                                     const int* __restrict__ boff,
                                                     int* __restrict__ row_ptr,
                                                     int* __restrict__ cursor,
                                                     float* __restrict__ dis, int n) {
  __shared__ int sd[256];
  int tid = threadIdx.x;
  int base = blockIdx.x * 1024 + tid * 4;
  int4 v = make_int4(0, 0, 0, 0);
  bool ok = (base + 4 <= n);
  if (ok) v = *(const int4*)&cnt[base];
  int s = v.x + v.y + v.z + v.w;
  sd[tid] = s;
  __syncthreads();
  for (int o = 1; o < 256; o <<= 1) {
    int t = (tid >= o) ? sd[tid - o] : 0;
    __syncthreads();
    sd[tid] += t;
    __syncthreads();
  }
  if (ok) {
    int run = boff[blockIdx.x] + sd[tid] - s;  // exclusive prefix
    int4 rp;
    rp.x = run;
    rp.y = run + v.x;
    rp.z = rp.y + v.y;
    rp.w = rp.z + v.z;
    *(int4*)&row_ptr[base] = rp;
    *(int4*)&cursor[base] = rp;
    float4 dv;
    dv.x = (v.x > 0) ? rsqrtf((float)v.x) : 0.f;
    dv.y = (v.y > 0) ? rsqrtf((float)v.y) : 0.f;
    dv.z = (v.z > 0) ? rsqrtf((float)v.z) : 0.f;
    dv.w = (v.w > 0) ? rsqrtf((float)v.w) : 0.f;
    *(float4*)&dis[base] = dv;
  }
}

// packed CSR entry: .x = src node, .y = f32 bits of norm
__global__ void scatter_kernel(const int* __restrict__ src, const int* __restrict__ dst,
                               const float* __restrict__ dis, int* __restrict__ cursor,
                               int2* __restrict__ csr, int e) {
  int i = blockIdx.x * blockDim.x + threadIdx.x;
  if (i < e) {
    int s = src[i], d = dst[i];
    int pos = atomicAdd(&cursor[d], 1);
    int2 ent;
    ent.x = s;
    ent.y = __float_as_int(dis[s] * dis[d]);
    csr[pos] = ent;
  }
}

// ---------------- weight transforms ----------------
// W1t[c][k] = bf16(W1[k][c]);  [128][512]
__global__ void w1t_kernel(const float* __restrict__ W1, unsigned short* __restrict__ W1t) {
  int t = blockIdx.x * blockDim.x + threadIdx.x;
  if (t < 512 * 128) {
    int c = t >> 9, k = t & 511;
    W1t[t] = f2bf(W1[(size_t)k * 128 + c]);
  }
}

// W2pt[q][r] = bf16(W2[(k*128+r)*40 + c]), q = k*40+c;  [160][128]
__global__ void w2pt_kernel(const float* __restrict__ W2, unsigned short* __restrict__ W2pt) {
  int t = blockIdx.x * blockDim.x + threadIdx.x;
  if (t < 160 * 128) {
    int q = t >> 7, r = t & 127;
    int k = q / 40, c = q - k * 40;
    W2pt[t] = f2bf(W2[(size_t)(k * 128 + r) * 40 + c]);
  }
}

// ---------------- x -> bf16 into P block 0 ----------------
__global__ void copyx_kernel(const float* __restrict__ x, unsigned short* __restrict__ P, int n) {
  int t = blockIdx.x * blockDim.x + threadIdx.x;
  int i = t >> 5;
  int c4 = (t & 31) << 2;
  if (i < n) {
    float4 v = *(const float4*)&x[(size_t)i * 128 + c4];
    unsigned lo = (unsigned)f2bf(v.x) | ((unsigned)f2bf(v.y) << 16);
    unsigned hi = (unsigned)f2bf(v.z) | ((unsigned)f2bf(v.w) << 16);
    uint2 o; o.x = lo; o.y = hi;
    *(uint2*)&P[(size_t)i * 512 + c4] = o;
  }
}

// ---------------- 128-dim bf16 propagation (wave per node) ----------------
__global__ __launch_bounds__(256) void prop128b_kernel(
    const unsigned short* __restrict__ in, unsigned short* __restrict__ out,
    const int* __restrict__ row_ptr, const int2* __restrict__ csr, int n) {
  int node = (int)((blockIdx.x * blockDim.x + threadIdx.x) >> 6);
  int lane = threadIdx.x & 63;
  if (node >= n) return;
  int beg = row_ptr[node], end = row_ptr[node + 1];
  float ax = 0.f, ay = 0.f;
  int j = beg;
  for (; j + 2 <= end; j += 2) {
    int2 e0 = csr[j], e1 = csr[j + 1];
    float w0 = __int_as_float(e0.y), w1 = __int_as_float(e1.y);
    unsigned p0 = *(const unsigned*)&in[(size_t)e0.x * 512 + 2 * lane];
    unsigned p1 = *(const unsigned*)&in[(size_t)e1.x * 512 + 2 * lane];
    ax = fmaf(w0, bflo(p0), ax); ay = fmaf(w0, bfhi(p0), ay);
    ax = fmaf(w1, bflo(p1), ax); ay = fmaf(w1, bfhi(p1), ay);
  }
  if (j < end) {
    int2 e0 = csr[j];
    float w0 = __int_as_float(e0.y);
    unsigned p0 = *(const unsigned*)&in[(size_t)e0.x * 512 + 2 * lane];
    ax = fmaf(w0, bflo(p0), ax); ay = fmaf(w0, bfhi(p0), ay);
  }
  unsigned o = (unsigned)f2bf(ax) | ((unsigned)f2bf(ay) << 16);
  *(unsigned*)&out[(size_t)node * 512 + 2 * lane] = o;
}

// ---------------- GEMM1 (MFMA): H = relu(P[N,512] @ W1 + b1), bf16 out ----------------
__global__ __launch_bounds__(256) void gemm1m_kernel(
    const unsigned short* __restrict__ A,    // [NROWP][512] bf16
    const unsigned short* __restrict__ Bt,   // [128][512] bf16 (W1 transposed)
    const float* __restrict__ bias,
    unsigned short* __restrict__ H) {        // [NROWP][128] bf16
  __shared__ short As[64 * 32];
  __shared__ short Bs[128 * 32];
  const int tid = threadIdx.x;
  const int lane = tid & 63;
  const int w = tid >> 6;
  const int wr = w & 1;
  const int wc = w >> 1;
  const int row0 = blockIdx.x * 64;
  f32x4 acc[2][4];
#pragma unroll
  for (int i = 0; i < 2; ++i)
#pragma unroll
    for (int j = 0; j < 4; ++j) acc[i][j] = (f32x4)0.f;

  const int lrow = lane >> 2;
  const int lkp = lane & 3;

  for (int k0 = 0; k0 < 512; k0 += 32) {
    gload_lds16(A + (size_t)(row0 + w * 16 + lrow) * 512 + k0 + lkp * 8, &As[w * 512]);
    gload_lds16(Bt + (size_t)(w * 16 + lrow) * 512 + k0 + lkp * 8, &Bs[w * 512]);
    gload_lds16(Bt + (size_t)((w + 4) * 16 + lrow) * 512 + k0 + lkp * 8, &Bs[(w + 4) * 512]);
    __syncthreads();
    const int kg = lane >> 4, rr = lane & 15;
    bf16x8 af[2], bfr[4];
#pragma unroll
    for (int mr = 0; mr < 2; ++mr)
      af[mr] = __builtin_bit_cast(bf16x8,
          *(const short8v*)&As[(wr * 32 + mr * 16 + rr) * 32 + kg * 8]);
#pragma unroll
    for (int nr = 0; nr < 4; ++nr)
      bfr[nr] = __builtin_bit_cast(bf16x8,
          *(const short8v*)&Bs[(wc * 64 + nr * 16 + rr) * 32 + kg * 8]);
#pragma unroll
    for (int mr = 0; mr < 2; ++mr)
#pragma unroll
      for (int nr = 0; nr < 4; ++nr)
        acc[mr][nr] = mfma_bf16(af[mr], bfr[nr], acc[mr][nr]);
    __syncthreads();
  }
  const int cg = lane >> 4, cl = lane & 15;
#pragma unroll
  for (int mr = 0; mr < 2; ++mr)
#pragma unroll
    for (int nr = 0; nr < 4; ++nr) {
      int col = wc * 64 + nr * 16 + cl;
      float bv = bias[col];
#pragma unroll
      for (int j = 0; j < 4; ++j) {
        int row = row0 + wr * 32 + mr * 16 + cg * 4 + j;
        H[(size_t)row * 128 + col] = f2bf(fmaxf(acc[mr][nr][j] + bv, 0.f));
      }
    }
}

// ---------------- GEMM2 (MFMA): Gk[N,40] bf16, k=0..3 (compact blocks) ----------------
__global__ __launch_bounds__(256) void gemm2m_kernel(
    const unsigned short* __restrict__ A,    // [NROWP][128] bf16
    const unsigned short* __restrict__ Bt,   // [160][128] bf16
    unsigned short* __restrict__ G) {        // 4 x [NROWP][40] bf16
  __shared__ short As[64 * 32];
  __shared__ short Bs[160 * 32];
  const int tid = threadIdx.x;
  const int lane = tid & 63;
  const int w = tid >> 6;
  const int row0 = blockIdx.x * 64;
  f32x4 acc[10];
#pragma unroll
  for (int i = 0; i < 10; ++i) acc[i] = (f32x4)0.f;
  const int lrow = lane >> 2, lkp = lane & 3;

  for (int k0 = 0; k0 < 128; k0 += 32) {
    gload_lds16(A + (size_t)(row0 + w * 16 + lrow) * 128 + k0 + lkp * 8, &As[w * 512]);
    for (int c = w; c < 10; c += 4)
      gload_lds16(Bt + (size_t)(c * 16 + lrow) * 128 + k0 + lkp * 8, &Bs[c * 512]);
    __syncthreads();
    const int kg = lane >> 4, rr = lane & 15;
    bf16x8 af = __builtin_bit_cast(bf16x8,
        *(const short8v*)&As[(w * 16 + rr) * 32 + kg * 8]);
#pragma unroll
    for (int nr = 0; nr < 10; ++nr) {
      bf16x8 bfr = __builtin_bit_cast(bf16x8,
          *(const short8v*)&Bs[(nr * 16 + rr) * 32 + kg * 8]);
      acc[nr] = mfma_bf16(af, bfr, acc[nr]);
    }
    __syncthreads();
  }
  const int cg = lane >> 4, cl = lane & 15;
#pragma unroll
  for (int nr = 0; nr < 10; ++nr) {
    int col = nr * 16 + cl;      // 0..159
    int k = col / 40;            // hop block
    int o = col - k * 40;
#pragma unroll
    for (int j = 0; j < 4; ++j) {
      int row = row0 + w * 16 + cg * 4 + j;
      G[(size_t)k * NROWP * 40 + (size_t)row * 40 + o] = f2bf(acc[nr][j]);
    }
  }
}

// ---------------- 40-dim bf16 propagation with additive term ----------------
__global__ __launch_bounds__(256) void prop40b_kernel(
    const unsigned short* __restrict__ in,
    const unsigned short* __restrict__ add,
    unsigned short* __restrict__ out,
    const int* __restrict__ row_ptr, const int2* __restrict__ csr, int n) {
  int node = (int)((blockIdx.x * blockDim.x + threadIdx.x) >> 6);
  int lane = threadIdx.x & 63;
  if (node >= n || lane >= 40) return;
  float acc = bf2f(add[(size_t)node * 40 + lane]);
  int beg = row_ptr[node], end = row_ptr[node + 1];
  int j = beg;
  for (; j + 2 <= end; j += 2) {
    int2 e0 = csr[j], e1 = csr[j + 1];
    float w0 = __int_as_float(e0.y), w1 = __int_as_float(e1.y);
    float v0 = bf2f(in[(size_t)e0.x * 40 + lane]);
    float v1 = bf2f(in[(size_t)e1.x * 40 + lane]);
    acc = fmaf(w0, v0, acc);
    acc = fmaf(w1, v1, acc);
  }
  if (j < end) {
    int2 e0 = csr[j];
    acc = fmaf(__int_as_float(e0.y), bf2f(in[(size_t)e0.x * 40 + lane]), acc);
  }
  out[(size_t)node * 40 + lane] = f2bf(acc);
}

// ---------------- final hop fused with bias + log_softmax ----------------
__global__ __launch_bounds__(256) void prop40b_lsm_kernel(
    const unsigned short* __restrict__ in,
    const unsigned short* __restrict__ add,
    const float* __restrict__ b2,
    float* __restrict__ out,
    const int* __restrict__ row_ptr, const int2* __restrict__ csr, int n) {
  int node = (int)((blockIdx.x * blockDim.x + threadIdx.x) >> 6);
  int lane = threadIdx.x & 63;
  if (node >= n) return;
  float acc = 0.f;
  if (lane < 40) {
    acc = bf2f(add[(size_t)node * 40 + lane]);
    int beg = row_ptr[node], end = row_ptr[node + 1];
    int j = beg;
    for (; j + 2 <= end; j += 2) {
      int2 e0 = csr[j], e1 = csr[j + 1];
      float w0 = __int_as_float(e0.y), w1 = __int_as_float(e1.y);
      float v0 = bf2f(in[(size_t)e0.x * 40 + lane]);
      float v1 = bf2f(in[(size_t)e1.x * 40 + lane]);
      acc = fmaf(w0, v0, acc);
      acc = fmaf(w1, v1, acc);
    }
    if (j < end) {
      int2 e0 = csr[j];
      acc = fmaf(__int_as_float(e0.y), bf2f(in[(size_t)e0.x * 40 + lane]), acc);
    }
  }
  float v = (lane < 40) ? acc + b2[lane] : -__builtin_inff();
  float m = v;
#pragma unroll
  for (int o = 32; o; o >>= 1) m = fmaxf(m, __shfl_xor(m, o, 64));
  float p = (lane < 40) ? expf(v - m) : 0.f;
  float s = p;
#pragma unroll
  for (int o = 32; o; o >>= 1) s += __shfl_xor(s, o, 64);
  if (lane < 40) out[(size_t)node * 40 + lane] = v - m - logf(s);
}

extern "C" void kernel_launch(void* const* d_in, const int* in_sizes, int n_in,
                              void* d_out, int out_size, void* d_ws, size_t ws_size,
                              hipStream_t stream) {
  const float* x  = (const float*)d_in[0];
  const int*   ei = (const int*)d_in[1];
  const float* W1 = (const float*)d_in[2];
  const float* b1 = (const float*)d_in[3];
  const float* W2 = (const float*)d_in[4];
  const float* b2 = (const float*)d_in[5];
  const int* srcv = ei;
  const int* dstv = ei + NEDGES;
  float* out = (float*)d_out;

  char* wsb = (char*)d_ws;
  size_t off = 0;
  auto alloc = [&](size_t bytes) {
    char* p = wsb + off;
    off += (bytes + 255) & ~(size_t)255;
    return p;
  };
  int*            cnt     = (int*)            alloc((size_t)NNODES * 4);
  float*          dis     = (float*)          alloc((size_t)NNODES * 4);
  int*            row_ptr = (int*)            alloc(((size_t)NNODES + 1) * 4);
  int*            cursor  = (int*)            alloc((size_t)NNODES * 4);
  int*            bsums   = (int*)            alloc((size_t)SCAN_NB * 4);
  int*            boff    = (int*)            alloc((size_t)SCAN_NB * 4);
  int2*           csr     = (int2*)           alloc((size_t)NEDGES * 8);
  unsigned short* W1t     = (unsigned short*) alloc((size_t)128 * 512 * 2);
  unsigned short* W2pt    = (unsigned short*) alloc((size_t)160 * 128 * 2);
  unsigned short* P       = (unsigned short*) alloc((size_t)NROWP * 512 * 2);
  unsigned short* H       = (unsigned short*) alloc((size_t)NROWP * 128 * 2);
  unsigned short* G       = (unsigned short*) alloc((size_t)4 * NROWP * 40 * 2);
  unsigned short* tb      = (unsigned short*) alloc((size_t)NNODES * 40 * 2);
  unsigned short* t2      = (unsigned short*) alloc((size_t)NNODES * 40 * 2);

  unsigned short* G0 = G;
  unsigned short* G1 = G + (size_t)1 * NROWP * 40;
  unsigned short* G2 = G + (size_t)2 * NROWP * 40;
  unsigned short* G3 = G + (size_t)3 * NROWP * 40;

  hipMemsetAsync(cnt, 0, (size_t)NNODES * 4, stream);
  hist_kernel<<<(NEDGES + 255) / 256, 256, 0, stream>>>(dstv, cnt, NEDGES);
  bsum_kernel<<<SCAN_NB, 256, 0, stream>>>(cnt, bsums, NNODES);
  bscan_kernel<<<1, 64, 0, stream>>>(bsums, boff, row_ptr, SCAN_NB, NNODES);
  bfinal_kernel<<<SCAN_NB, 256, 0, stream>>>(cnt, boff, row_ptr, cursor, dis, NNODES);
  scatter_kernel<<<(NEDGES + 255) / 256, 256, 0, stream>>>(srcv, dstv, dis, cursor,
                                                           csr, NEDGES);
  w1t_kernel<<<(512 * 128 + 255) / 256, 256, 0, stream>>>(W1, W1t);
  w2pt_kernel<<<(160 * 128 + 255) / 256, 256, 0, stream>>>(W2, W2pt);
  copyx_kernel<<<((NNODES * 32) + 255) / 256, 256, 0, stream>>>(x, P, NNODES);

  const int prop_blocks = (NNODES * 64 + 255) / 256;
  // Layer 1: P blocks k = A_hat^k x  (bf16, row stride 512)
  for (int k = 1; k <= KHOP; ++k)
    prop128b_kernel<<<prop_blocks, 256, 0, stream>>>(P + 128 * (k - 1), P + 128 * k,
                                                     row_ptr, csr, NNODES);
  const int gemm_blocks = (NNODES + 63) / 64;  // 784; rows < NROWP
  gemm1m_kernel<<<gemm_blocks, 256, 0, stream>>>(P, W1t, b1, H);
  gemm2m_kernel<<<gemm_blocks, 256, 0, stream>>>(H, W2pt, G);
  // Horner (bf16 storage, fp32 accum): tb = A*G3 + G2 ; t2 = A*tb + G1 ; out = lsm(A*t2 + G0 + b2)
  prop40b_kernel<<<prop_blocks, 256, 0, stream>>>(G3, G2, tb, row_ptr, csr, NNODES);
  prop40b_kernel<<<prop_blocks, 256, 0, stream>>>(tb, G1, t2, row_ptr, csr, NNODES);
  prop40b_lsm_kernel<<<prop_blocks, 256, 0, stream>>>(t2, G0, b2, out, row_ptr, csr, NNODES);
}

// Round 5
// 305.400 us; speedup vs baseline: 2.3253x; 1.3270x over previous
//
#include <hip/hip_runtime.h>
#include <hip/hip_bf16.h>

#define NNODES 50000
#define NROWP  50176   // padded row count (multiple of 64) for GEMM tiles
#define NEDGES 800000
#define KHOP 3
#define SCAN_NB 49     // ceil(NNODES / 1024)

typedef __attribute__((ext_vector_type(8))) short short8v;
typedef __attribute__((ext_vector_type(8))) __bf16 bf16x8;
typedef __attribute__((ext_vector_type(4))) float f32x4;

__device__ inline unsigned short f2bf(float f) {
  unsigned u = __builtin_bit_cast(unsigned, f);
  u += 0x7fffu + ((u >> 16) & 1u);   // RNE
  return (unsigned short)(u >> 16);
}
__device__ inline float bf2f(unsigned short h) {
  return __builtin_bit_cast(float, (unsigned)h << 16);
}
__device__ inline float bflo(unsigned u) { return __builtin_bit_cast(float, u << 16); }
__device__ inline float bfhi(unsigned u) { return __builtin_bit_cast(float, u & 0xffff0000u); }

__device__ inline void gload_lds16(const void* g, void* l) {
  __builtin_amdgcn_global_load_lds(
      (const __attribute__((address_space(1))) unsigned int*)g,
      (__attribute__((address_space(3))) unsigned int*)l, 16, 0, 0);
}

__device__ inline f32x4 mfma_bf16(bf16x8 a, bf16x8 b, f32x4 c) {
  return __builtin_amdgcn_mfma_f32_16x16x32_bf16(a, b, c, 0, 0, 0);
}

// ---------------- CSR build ----------------
__global__ void hist_kernel(const int* __restrict__ dst, int* __restrict__ cnt, int e) {
  int i = blockIdx.x * blockDim.x + threadIdx.x;
  if (i < e) atomicAdd(&cnt[dst[i]], 1);
}

// --- hierarchical exclusive scan: bsum -> bscan -> bfinal (+dis fused) ---
__global__ __launch_bounds__(256) void bsum_kernel(const int* __restrict__ cnt,
                                                   int* __restrict__ bsums, int n) {
  __shared__ int sd[256];
  int tid = threadIdx.x;
  int base = blockIdx.x * 1024 + tid * 4;
  int s = 0;
  if (base + 4 <= n) {
    int4 v = *(const int4*)&cnt[base];
    s = v.x + v.y + v.z + v.w;
  }
  sd[tid] = s;
  __syncthreads();
  for (int o = 128; o; o >>= 1) {
    if (tid < o) sd[tid] += sd[tid + o];
    __syncthreads();
  }
  if (tid == 0) bsums[blockIdx.x] = sd[0];
}

__global__ __launch_bounds__(64) void bscan_kernel(const int* __restrict__ bsums,
                                                   int* __restrict__ boff,
                                                   int* __restrict__ row_ptr,
                                                   int nb, int n) {
  int tid = threadIdx.x;
  int own = (tid < nb) ? bsums[tid] : 0;
  int v = own;
#pragma unroll
  for (int o = 1; o < 64; o <<= 1) {
    int t = __shfl_up(v, o, 64);
    if (tid >= o) v += t;
  }
  if (tid < nb) boff[tid] = v - own;   // exclusive block offset
  if (tid == 63) row_ptr[n] = v;       // total edge count
}

__global__ __launch_bounds__(256) void bfinal_kernel(const int* __restrict__ cnt,
                                                     const int* __restrict__ boff,
                                                     int* __restrict__ row_ptr,
                                                     int* __restrict__ cursor,
                                                     float* __restrict__ dis, int n) {
  __shared__ int sd[256];
  int tid = threadIdx.x;
  int base = blockIdx.x * 1024 + tid * 4;
  int4 v = make_int4(0, 0, 0, 0);
  bool ok = (base + 4 <= n);
  if (ok) v = *(const int4*)&cnt[base];
  int s = v.x + v.y + v.z + v.w;
  sd[tid] = s;
  __syncthreads();
  for (int o = 1; o < 256; o <<= 1) {
    int t = (tid >= o) ? sd[tid - o] : 0;
    __syncthreads();
    sd[tid] += t;
    __syncthreads();
  }
  if (ok) {
    int run = boff[blockIdx.x] + sd[tid] - s;  // exclusive prefix
    int4 rp;
    rp.x = run;
    rp.y = run + v.x;
    rp.z = rp.y + v.y;
    rp.w = rp.z + v.z;
    *(int4*)&row_ptr[base] = rp;
    *(int4*)&cursor[base] = rp;
    float4 dv;
    dv.x = (v.x > 0) ? rsqrtf((float)v.x) : 0.f;
    dv.y = (v.y > 0) ? rsqrtf((float)v.y) : 0.f;
    dv.z = (v.z > 0) ? rsqrtf((float)v.z) : 0.f;
    dv.w = (v.w > 0) ? rsqrtf((float)v.w) : 0.f;
    *(float4*)&dis[base] = dv;
  }
}

// packed CSR entry: .x = src node, .y = f32 bits of norm
__global__ void scatter_kernel(const int* __restrict__ src, const int* __restrict__ dst,
                               const float* __restrict__ dis, int* __restrict__ cursor,
                               int2* __restrict__ csr, int e) {
  int i = blockIdx.x * blockDim.x + threadIdx.x;
  if (i < e) {
    int s = src[i], d = dst[i];
    int pos = atomicAdd(&cursor[d], 1);
    int2 ent;
    ent.x = s;
    ent.y = __float_as_int(dis[s] * dis[d]);
    csr[pos] = ent;
  }
}

// ---------------- weight transforms ----------------
// W1t[c][k] = bf16(W1[k][c]);  [128][512]
__global__ void w1t_kernel(const float* __restrict__ W1, unsigned short* __restrict__ W1t) {
  int t = blockIdx.x * blockDim.x + threadIdx.x;
  if (t < 512 * 128) {
    int c = t >> 9, k = t & 511;
    W1t[t] = f2bf(W1[(size_t)k * 128 + c]);
  }
}

// W2pt[q][r] = bf16(W2[(k*128+r)*40 + c]), q = k*40+c;  [160][128]
__global__ void w2pt_kernel(const float* __restrict__ W2, unsigned short* __restrict__ W2pt) {
  int t = blockIdx.x * blockDim.x + threadIdx.x;
  if (t < 160 * 128) {
    int q = t >> 7, r = t & 127;
    int k = q / 40, c = q - k * 40;
    W2pt[t] = f2bf(W2[(size_t)(k * 128 + r) * 40 + c]);
  }
}

// ---------------- x -> bf16 into P block 0 ----------------
__global__ void copyx_kernel(const float* __restrict__ x, unsigned short* __restrict__ P, int n) {
  int t = blockIdx.x * blockDim.x + threadIdx.x;
  int i = t >> 5;
  int c4 = (t & 31) << 2;
  if (i < n) {
    float4 v = *(const float4*)&x[(size_t)i * 128 + c4];
    unsigned lo = (unsigned)f2bf(v.x) | ((unsigned)f2bf(v.y) << 16);
    unsigned hi = (unsigned)f2bf(v.z) | ((unsigned)f2bf(v.w) << 16);
    uint2 o; o.x = lo; o.y = hi;
    *(uint2*)&P[(size_t)i * 512 + c4] = o;
  }
}

// ---------------- 128-dim bf16 propagation (wave per node, shfl-broadcast CSR) ----------------
__global__ __launch_bounds__(256) void prop128b_kernel(
    const unsigned short* __restrict__ in, unsigned short* __restrict__ out,
    const int* __restrict__ row_ptr, const int2* __restrict__ csr, int n) {
  int node = (int)((blockIdx.x * blockDim.x + threadIdx.x) >> 6);
  int lane = threadIdx.x & 63;
  if (node >= n) return;
  int beg = row_ptr[node], end = row_ptr[node + 1];
  int deg = end - beg;
  // lane-distributed preload of up to 64 CSR entries
  int2 ent = make_int2(0, 0);
  if (lane < deg) ent = csr[beg + lane];
  float ax = 0.f, ay = 0.f;
  int m = deg < 64 ? deg : 64;
  int j = 0;
  for (; j + 4 <= m; j += 4) {
    int s0 = __shfl(ent.x, j, 64);
    int s1 = __shfl(ent.x, j + 1, 64);
    int s2 = __shfl(ent.x, j + 2, 64);
    int s3 = __shfl(ent.x, j + 3, 64);
    float w0 = __int_as_float(__shfl(ent.y, j, 64));
    float w1 = __int_as_float(__shfl(ent.y, j + 1, 64));
    float w2 = __int_as_float(__shfl(ent.y, j + 2, 64));
    float w3 = __int_as_float(__shfl(ent.y, j + 3, 64));
    unsigned p0 = *(const unsigned*)&in[(size_t)s0 * 512 + 2 * lane];
    unsigned p1 = *(const unsigned*)&in[(size_t)s1 * 512 + 2 * lane];
    unsigned p2 = *(const unsigned*)&in[(size_t)s2 * 512 + 2 * lane];
    unsigned p3 = *(const unsigned*)&in[(size_t)s3 * 512 + 2 * lane];
    ax = fmaf(w0, bflo(p0), ax); ay = fmaf(w0, bfhi(p0), ay);
    ax = fmaf(w1, bflo(p1), ax); ay = fmaf(w1, bfhi(p1), ay);
    ax = fmaf(w2, bflo(p2), ax); ay = fmaf(w2, bfhi(p2), ay);
    ax = fmaf(w3, bflo(p3), ax); ay = fmaf(w3, bfhi(p3), ay);
  }
  for (; j < m; ++j) {
    int s0 = __shfl(ent.x, j, 64);
    float w0 = __int_as_float(__shfl(ent.y, j, 64));
    unsigned p0 = *(const unsigned*)&in[(size_t)s0 * 512 + 2 * lane];
    ax = fmaf(w0, bflo(p0), ax); ay = fmaf(w0, bfhi(p0), ay);
  }
  // rare tail: deg > 64
  for (int t = beg + 64; t < end; ++t) {
    int2 e0 = csr[t];
    float w0 = __int_as_float(e0.y);
    unsigned p0 = *(const unsigned*)&in[(size_t)e0.x * 512 + 2 * lane];
    ax = fmaf(w0, bflo(p0), ax); ay = fmaf(w0, bfhi(p0), ay);
  }
  unsigned o = (unsigned)f2bf(ax) | ((unsigned)f2bf(ay) << 16);
  *(unsigned*)&out[(size_t)node * 512 + 2 * lane] = o;
}

// ---------------- GEMM1 (MFMA): H = relu(P[N,512] @ W1 + b1), bf16 out ----------------
__global__ __launch_bounds__(256) void gemm1m_kernel(
    const unsigned short* __restrict__ A,    // [NROWP][512] bf16
    const unsigned short* __restrict__ Bt,   // [128][512] bf16 (W1 transposed)
    const float* __restrict__ bias,
    unsigned short* __restrict__ H) {        // [NROWP][128] bf16
  __shared__ short As[64 * 32];
  __shared__ short Bs[128 * 32];
  const int tid = threadIdx.x;
  const int lane = tid & 63;
  const int w = tid >> 6;
  const int wr = w & 1;
  const int wc = w >> 1;
  const int row0 = blockIdx.x * 64;
  f32x4 acc[2][4];
#pragma unroll
  for (int i = 0; i < 2; ++i)
#pragma unroll
    for (int j = 0; j < 4; ++j) acc[i][j] = (f32x4)0.f;

  const int lrow = lane >> 2;
  const int lkp = lane & 3;

  for (int k0 = 0; k0 < 512; k0 += 32) {
    gload_lds16(A + (size_t)(row0 + w * 16 + lrow) * 512 + k0 + lkp * 8, &As[w * 512]);
    gload_lds16(Bt + (size_t)(w * 16 + lrow) * 512 + k0 + lkp * 8, &Bs[w * 512]);
    gload_lds16(Bt + (size_t)((w + 4) * 16 + lrow) * 512 + k0 + lkp * 8, &Bs[(w + 4) * 512]);
    __syncthreads();
    const int kg = lane >> 4, rr = lane & 15;
    bf16x8 af[2], bfr[4];
#pragma unroll
    for (int mr = 0; mr < 2; ++mr)
      af[mr] = __builtin_bit_cast(bf16x8,
          *(const short8v*)&As[(wr * 32 + mr * 16 + rr) * 32 + kg * 8]);
#pragma unroll
    for (int nr = 0; nr < 4; ++nr)
      bfr[nr] = __builtin_bit_cast(bf16x8,
          *(const short8v*)&Bs[(wc * 64 + nr * 16 + rr) * 32 + kg * 8]);
#pragma unroll
    for (int mr = 0; mr < 2; ++mr)
#pragma unroll
      for (int nr = 0; nr < 4; ++nr)
        acc[mr][nr] = mfma_bf16(af[mr], bfr[nr], acc[mr][nr]);
    __syncthreads();
  }
  const int cg = lane >> 4, cl = lane & 15;
#pragma unroll
  for (int mr = 0; mr < 2; ++mr)
#pragma unroll
    for (int nr = 0; nr < 4; ++nr) {
      int col = wc * 64 + nr * 16 + cl;
      float bv = bias[col];
#pragma unroll
      for (int j = 0; j < 4; ++j) {
        int row = row0 + wr * 32 + mr * 16 + cg * 4 + j;
        H[(size_t)row * 128 + col] = f2bf(fmaxf(acc[mr][nr][j] + bv, 0.f));
      }
    }
}

// ---------------- GEMM2 (MFMA): Gk[N,40] bf16, k=0..3 (compact blocks) ----------------
__global__ __launch_bounds__(256) void gemm2m_kernel(
    const unsigned short* __restrict__ A,    // [NROWP][128] bf16
    const unsigned short* __restrict__ Bt,   // [160][128] bf16
    unsigned short* __restrict__ G) {        // 4 x [NROWP][40] bf16
  __shared__ short As[64 * 32];
  __shared__ short Bs[160 * 32];
  const int tid = threadIdx.x;
  const int lane = tid & 63;
  const int w = tid >> 6;
  const int row0 = blockIdx.x * 64;
  f32x4 acc[10];
#pragma unroll
  for (int i = 0; i < 10; ++i) acc[i] = (f32x4)0.f;
  const int lrow = lane >> 2, lkp = lane & 3;

  for (int k0 = 0; k0 < 128; k0 += 32) {
    gload_lds16(A + (size_t)(row0 + w * 16 + lrow) * 128 + k0 + lkp * 8, &As[w * 512]);
    for (int c = w; c < 10; c += 4)
      gload_lds16(Bt + (size_t)(c * 16 + lrow) * 128 + k0 + lkp * 8, &Bs[c * 512]);
    __syncthreads();
    const int kg = lane >> 4, rr = lane & 15;
    bf16x8 af = __builtin_bit_cast(bf16x8,
        *(const short8v*)&As[(w * 16 + rr) * 32 + kg * 8]);
#pragma unroll
    for (int nr = 0; nr < 10; ++nr) {
      bf16x8 bfr = __builtin_bit_cast(bf16x8,
          *(const short8v*)&Bs[(nr * 16 + rr) * 32 + kg * 8]);
      acc[nr] = mfma_bf16(af, bfr, acc[nr]);
    }
    __syncthreads();
  }
  const int cg = lane >> 4, cl = lane & 15;
#pragma unroll
  for (int nr = 0; nr < 10; ++nr) {
    int col = nr * 16 + cl;      // 0..159
    int k = col / 40;            // hop block
    int o = col - k * 40;
#pragma unroll
    for (int j = 0; j < 4; ++j) {
      int row = row0 + w * 16 + cg * 4 + j;
      G[(size_t)k * NROWP * 40 + (size_t)row * 40 + o] = f2bf(acc[nr][j]);
    }
  }
}

// ---------------- 40-dim bf16 propagation with additive term (shfl CSR) ----------------
__global__ __launch_bounds__(256) void prop40b_kernel(
    const unsigned short* __restrict__ in,
    const unsigned short* __restrict__ add,
    unsigned short* __restrict__ out,
    const int* __restrict__ row_ptr, const int2* __restrict__ csr, int n) {
  int node = (int)((blockIdx.x * blockDim.x + threadIdx.x) >> 6);
  int lane = threadIdx.x & 63;
  if (node >= n) return;
  int beg = row_ptr[node], end = row_ptr[node + 1];
  int deg = end - beg;
  int2 ent = make_int2(0, 0);
  if (lane < deg) ent = csr[beg + lane];
  float acc = (lane < 40) ? bf2f(add[(size_t)node * 40 + lane]) : 0.f;
  int m = deg < 64 ? deg : 64;
  int j = 0;
  for (; j + 4 <= m; j += 4) {
    int s0 = __shfl(ent.x, j, 64);
    int s1 = __shfl(ent.x, j + 1, 64);
    int s2 = __shfl(ent.x, j + 2, 64);
    int s3 = __shfl(ent.x, j + 3, 64);
    float w0 = __int_as_float(__shfl(ent.y, j, 64));
    float w1 = __int_as_float(__shfl(ent.y, j + 1, 64));
    float w2 = __int_as_float(__shfl(ent.y, j + 2, 64));
    float w3 = __int_as_float(__shfl(ent.y, j + 3, 64));
    if (lane < 40) {
      float v0 = bf2f(in[(size_t)s0 * 40 + lane]);
      float v1 = bf2f(in[(size_t)s1 * 40 + lane]);
      float v2 = bf2f(in[(size_t)s2 * 40 + lane]);
      float v3 = bf2f(in[(size_t)s3 * 40 + lane]);
      acc = fmaf(w0, v0, acc);
      acc = fmaf(w1, v1, acc);
      acc = fmaf(w2, v2, acc);
      acc = fmaf(w3, v3, acc);
    }
  }
  for (; j < m; ++j) {
    int s0 = __shfl(ent.x, j, 64);
    float w0 = __int_as_float(__shfl(ent.y, j, 64));
    if (lane < 40) acc = fmaf(w0, bf2f(in[(size_t)s0 * 40 + lane]), acc);
  }
  for (int t = beg + 64; t < end; ++t) {
    int2 e0 = csr[t];
    if (lane < 40)
      acc = fmaf(__int_as_float(e0.y), bf2f(in[(size_t)e0.x * 40 + lane]), acc);
  }
  if (lane < 40) out[(size_t)node * 40 + lane] = f2bf(acc);
}

// ---------------- final hop fused with bias + log_softmax ----------------
__global__ __launch_bounds__(256) void prop40b_lsm_kernel(
    const unsigned short* __restrict__ in,
    const unsigned short* __restrict__ add,
    const float* __restrict__ b2,
    float* __restrict__ out,
    const int* __restrict__ row_ptr, const int2* __restrict__ csr, int n) {
  int node = (int)((blockIdx.x * blockDim.x + threadIdx.x) >> 6);
  int lane = threadIdx.x & 63;
  if (node >= n) return;
  int beg = row_ptr[node], end = row_ptr[node + 1];
  int deg = end - beg;
  int2 ent = make_int2(0, 0);
  if (lane < deg) ent = csr[beg + lane];
  float acc = (lane < 40) ? bf2f(add[(size_t)node * 40 + lane]) : 0.f;
  int m = deg < 64 ? deg : 64;
  int j = 0;
  for (; j + 4 <= m; j += 4) {
    int s0 = __shfl(ent.x, j, 64);
    int s1 = __shfl(ent.x, j + 1, 64);
    int s2 = __shfl(ent.x, j + 2, 64);
    int s3 = __shfl(ent.x, j + 3, 64);
    float w0 = __int_as_float(__shfl(ent.y, j, 64));
    float w1 = __int_as_float(__shfl(ent.y, j + 1, 64));
    float w2 = __int_as_float(__shfl(ent.y, j + 2, 64));
    float w3 = __int_as_float(__shfl(ent.y, j + 3, 64));
    if (lane < 40) {
      float v0 = bf2f(in[(size_t)s0 * 40 + lane]);
      float v1 = bf2f(in[(size_t)s1 * 40 + lane]);
      float v2 = bf2f(in[(size_t)s2 * 40 + lane]);
      float v3 = bf2f(in[(size_t)s3 * 40 + lane]);
      acc = fmaf(w0, v0, acc);
      acc = fmaf(w1, v1, acc);
      acc = fmaf(w2, v2, acc);
      acc = fmaf(w3, v3, acc);
    }
  }
  for (; j < m; ++j) {
    int s0 = __shfl(ent.x, j, 64);
    float w0 = __int_as_float(__shfl(ent.y, j, 64));
    if (lane < 40) acc = fmaf(w0, bf2f(in[(size_t)s0 * 40 + lane]), acc);
  }
  for (int t = beg + 64; t < end; ++t) {
    int2 e0 = csr[t];
    if (lane < 40)
      acc = fmaf(__int_as_float(e0.y), bf2f(in[(size_t)e0.x * 40 + lane]), acc);
  }
  float v = (lane < 40) ? acc + b2[lane] : -__builtin_inff();
  float mx = v;
#pragma unroll
  for (int o = 32; o; o >>= 1) mx = fmaxf(mx, __shfl_xor(mx, o, 64));
  float p = (lane < 40) ? expf(v - mx) : 0.f;
  float s = p;
#pragma unroll
  for (int o = 32; o; o >>= 1) s += __shfl_xor(s, o, 64);
  if (lane < 40) out[(size_t)node * 40 + lane] = v - mx - logf(s);
}

extern "C" void kernel_launch(void* const* d_in, const int* in_sizes, int n_in,
                              void* d_out, int out_size, void* d_ws, size_t ws_size,
                              hipStream_t stream) {
  const float* x  = (const float*)d_in[0];
  const int*   ei = (const int*)d_in[1];
  const float* W1 = (const float*)d_in[2];
  const float* b1 = (const float*)d_in[3];
  const float* W2 = (const float*)d_in[4];
  const float* b2 = (const float*)d_in[5];
  const int* srcv = ei;
  const int* dstv = ei + NEDGES;
  float* out = (float*)d_out;

  char* wsb = (char*)d_ws;
  size_t off = 0;
  auto alloc = [&](size_t bytes) {
    char* p = wsb + off;
    off += (bytes + 255) & ~(size_t)255;
    return p;
  };
  int*            cnt     = (int*)            alloc((size_t)NNODES * 4);
  float*          dis     = (float*)          alloc((size_t)NNODES * 4);
  int*            row_ptr = (int*)            alloc(((size_t)NNODES + 1) * 4);
  int*            cursor  = (int*)            alloc((size_t)NNODES * 4);
  int*            bsums   = (int*)            alloc((size_t)SCAN_NB * 4);
  int*            boff    = (int*)            alloc((size_t)SCAN_NB * 4);
  int2*           csr     = (int2*)           alloc((size_t)NEDGES * 8);
  unsigned short* W1t     = (unsigned short*) alloc((size_t)128 * 512 * 2);
  unsigned short* W2pt    = (unsigned short*) alloc((size_t)160 * 128 * 2);
  unsigned short* P       = (unsigned short*) alloc((size_t)NROWP * 512 * 2);
  unsigned short* H       = (unsigned short*) alloc((size_t)NROWP * 128 * 2);
  unsigned short* G       = (unsigned short*) alloc((size_t)4 * NROWP * 40 * 2);
  unsigned short* tb      = (unsigned short*) alloc((size_t)NNODES * 40 * 2);
  unsigned short* t2      = (unsigned short*) alloc((size_t)NNODES * 40 * 2);

  unsigned short* G0 = G;
  unsigned short* G1 = G + (size_t)1 * NROWP * 40;
  unsigned short* G2 = G + (size_t)2 * NROWP * 40;
  unsigned short* G3 = G + (size_t)3 * NROWP * 40;

  hipMemsetAsync(cnt, 0, (size_t)NNODES * 4, stream);
  hist_kernel<<<(NEDGES + 255) / 256, 256, 0, stream>>>(dstv, cnt, NEDGES);
  bsum_kernel<<<SCAN_NB, 256, 0, stream>>>(cnt, bsums, NNODES);
  bscan_kernel<<<1, 64, 0, stream>>>(bsums, boff, row_ptr, SCAN_NB, NNODES);
  bfinal_kernel<<<SCAN_NB, 256, 0, stream>>>(cnt, boff, row_ptr, cursor, dis, NNODES);
  scatter_kernel<<<(NEDGES + 255) / 256, 256, 0, stream>>>(srcv, dstv, dis, cursor,
                                                           csr, NEDGES);
  w1t_kernel<<<(512 * 128 + 255) / 256, 256, 0, stream>>>(W1, W1t);
  w2pt_kernel<<<(160 * 128 + 255) / 256, 256, 0, stream>>>(W2, W2pt);
  copyx_kernel<<<((NNODES * 32) + 255) / 256, 256, 0, stream>>>(x, P, NNODES);

  const int prop_blocks = (NNODES * 64 + 255) / 256;
  // Layer 1: P blocks k = A_hat^k x  (bf16, row stride 512)
  for (int k = 1; k <= KHOP; ++k)
    prop128b_kernel<<<prop_blocks, 256, 0, stream>>>(P + 128 * (k - 1), P + 128 * k,
                                                     row_ptr, csr, NNODES);
  const int gemm_blocks = (NNODES + 63) / 64;  // 784; rows < NROWP
  gemm1m_kernel<<<gemm_blocks, 256, 0, stream>>>(P, W1t, b1, H);
  gemm2m_kernel<<<gemm_blocks, 256, 0, stream>>>(H, W2pt, G);
  // Horner (bf16 storage, fp32 accum): tb = A*G3 + G2 ; t2 = A*tb + G1 ; out = lsm(A*t2 + G0 + b2)
  prop40b_kernel<<<prop_blocks, 256, 0, stream>>>(G3, G2, tb, row_ptr, csr, NNODES);
  prop40b_kernel<<<prop_blocks, 256, 0, stream>>>(tb, G1, t2, row_ptr, csr, NNODES);
  prop40b_lsm_kernel<<<prop_blocks, 256, 0, stream>>>(t2, G0, b2, out, row_ptr, csr, NNODES);
}

// Round 6
// 259.607 us; speedup vs baseline: 2.7354x; 1.1764x over previous
//
#include <hip/hip_runtime.h>
#include <hip/hip_bf16.h>

#define NNODES 50000
#define NROWP  50176   // padded row count (multiple of 64) for GEMM tiles
#define NEDGES 800000
#define KHOP 3
#define SCAN_NB 49     // ceil(NNODES / 1024)
#define NBKT 196       // ceil(50176/256) buckets of 256 nodes
#define BCAP 6144      // entries per bucket (mean 4082, sd ~64 -> safe)
#define ABLK 400       // pass-A blocks
#define ACH  2000      // edges per pass-A block

typedef __attribute__((ext_vector_type(8))) short short8v;
typedef __attribute__((ext_vector_type(8))) __bf16 bf16x8;
typedef __attribute__((ext_vector_type(4))) float f32x4;

__device__ inline unsigned short f2bf(float f) {
  unsigned u = __builtin_bit_cast(unsigned, f);
  u += 0x7fffu + ((u >> 16) & 1u);   // RNE
  return (unsigned short)(u >> 16);
}
__device__ inline float bf2f(unsigned short h) {
  return __builtin_bit_cast(float, (unsigned)h << 16);
}
__device__ inline float bflo(unsigned u) { return __builtin_bit_cast(float, u << 16); }
__device__ inline float bfhi(unsigned u) { return __builtin_bit_cast(float, u & 0xffff0000u); }

__device__ inline void gload_lds16(const void* g, void* l) {
  __builtin_amdgcn_global_load_lds(
      (const __attribute__((address_space(1))) unsigned int*)g,
      (__attribute__((address_space(3))) unsigned int*)l, 16, 0, 0);
}

__device__ inline f32x4 mfma_bf16(bf16x8 a, bf16x8 b, f32x4 c) {
  return __builtin_amdgcn_mfma_f32_16x16x32_bf16(a, b, c, 0, 0, 0);
}

// ---------------- Pass A: bucket edges by dst>>8 ----------------
__global__ __launch_bounds__(256) void bucketA_kernel(
    const int* __restrict__ src, const int* __restrict__ dst,
    int* __restrict__ bcur, int2* __restrict__ bkt) {
  __shared__ int2 eb[ACH];
  __shared__ int hist[256];
  __shared__ int base[256];
  int tid = threadIdx.x;
  int e0 = blockIdx.x * ACH;
  int cnt = NEDGES - e0; if (cnt > ACH) cnt = ACH;
  hist[tid] = 0;
  __syncthreads();
  for (int i = tid; i < cnt; i += 256) {
    int s = src[e0 + i], d = dst[e0 + i];
    eb[i] = make_int2(s, d);
    atomicAdd(&hist[d >> 8], 1);
  }
  __syncthreads();
  base[tid] = atomicAdd(&bcur[tid], hist[tid]);
  hist[tid] = 0;
  __syncthreads();
  for (int i = tid; i < cnt; i += 256) {
    int2 e = eb[i];
    int b = e.y >> 8;
    int off = atomicAdd(&hist[b], 1);
    bkt[(size_t)b * BCAP + base[b] + off] = e;
  }
}

// ---------------- per-bucket node histogram (replaces global-atomic hist) ----------------
__global__ __launch_bounds__(256) void histB_kernel(
    const int* __restrict__ bcur, const int2* __restrict__ bkt,
    int* __restrict__ cnt, int n) {
  __shared__ int h[256];
  int b = blockIdx.x, tid = threadIdx.x;
  h[tid] = 0;
  __syncthreads();
  int sz = bcur[b];
  for (int i = tid; i < sz; i += 256)
    atomicAdd(&h[bkt[(size_t)b * BCAP + i].y & 255], 1);
  __syncthreads();
  int node = b * 256 + tid;
  if (node < n) cnt[node] = h[tid];
}

// --- hierarchical exclusive scan: bsum -> bscan -> bfinal (+dis fused) ---
__global__ __launch_bounds__(256) void bsum_kernel(const int* __restrict__ cnt,
                                                   int* __restrict__ bsums, int n) {
  __shared__ int sd[256];
  int tid = threadIdx.x;
  int base = blockIdx.x * 1024 + tid * 4;
  int s = 0;
  if (base + 4 <= n) {
    int4 v = *(const int4*)&cnt[base];
    s = v.x + v.y + v.z + v.w;
  }
  sd[tid] = s;
  __syncthreads();
  for (int o = 128; o; o >>= 1) {
    if (tid < o) sd[tid] += sd[tid + o];
    __syncthreads();
  }
  if (tid == 0) bsums[blockIdx.x] = sd[0];
}

__global__ __launch_bounds__(64) void bscan_kernel(const int* __restrict__ bsums,
                                                   int* __restrict__ boff,
                                                   int* __restrict__ row_ptr,
                                                   int nb, int n) {
  int tid = threadIdx.x;
  int own = (tid < nb) ? bsums[tid] : 0;
  int v = own;
#pragma unroll
  for (int o = 1; o < 64; o <<= 1) {
    int t = __shfl_up(v, o, 64);
    if (tid >= o) v += t;
  }
  if (tid < nb) boff[tid] = v - own;   // exclusive block offset
  if (tid == 63) row_ptr[n] = v;       // total edge count
}

__global__ __launch_bounds__(256) void bfinal_kernel(const int* __restrict__ cnt,
                                                     const int* __restrict__ boff,
                                                     int* __restrict__ row_ptr,
                                                     float* __restrict__ dis, int n) {
  __shared__ int sd[256];
  int tid = threadIdx.x;
  int base = blockIdx.x * 1024 + tid * 4;
  int4 v = make_int4(0, 0, 0, 0);
  bool ok = (base + 4 <= n);
  if (ok) v = *(const int4*)&cnt[base];
  int s = v.x + v.y + v.z + v.w;
  sd[tid] = s;
  __syncthreads();
  for (int o = 1; o < 256; o <<= 1) {
    int t = (tid >= o) ? sd[tid - o] : 0;
    __syncthreads();
    sd[tid] += t;
    __syncthreads();
  }
  if (ok) {
    int run = boff[blockIdx.x] + sd[tid] - s;  // exclusive prefix
    int4 rp;
    rp.x = run;
    rp.y = run + v.x;
    rp.z = rp.y + v.y;
    rp.w = rp.z + v.z;
    *(int4*)&row_ptr[base] = rp;
    float4 dv;
    dv.x = (v.x > 0) ? rsqrtf((float)v.x) : 0.f;
    dv.y = (v.y > 0) ? rsqrtf((float)v.y) : 0.f;
    dv.z = (v.z > 0) ? rsqrtf((float)v.z) : 0.f;
    dv.w = (v.w > 0) ? rsqrtf((float)v.w) : 0.f;
    *(float4*)&dis[base] = dv;
  }
}

// ---------------- Pass B: per-bucket scatter into CSR (L2-local writes) ----------------
__global__ __launch_bounds__(256) void scatB_kernel(
    const int* __restrict__ bcur, const int2* __restrict__ bkt,
    const int* __restrict__ row_ptr, const float* __restrict__ dis,
    int2* __restrict__ csr, int n) {
  __shared__ int cur[256];
  int b = blockIdx.x, tid = threadIdx.x;
  int node = b * 256 + tid;
  cur[tid] = (node < n) ? row_ptr[node] : 0;
  __syncthreads();
  int sz = bcur[b];
  for (int i = tid; i < sz; i += 256) {
    int2 e = bkt[(size_t)b * BCAP + i];
    int pos = atomicAdd(&cur[e.y & 255], 1);
    int2 ent;
    ent.x = e.x;
    ent.y = __float_as_int(dis[e.x] * dis[e.y]);
    csr[pos] = ent;
  }
}

// ---------------- fused weight transforms ----------------
// W1t[c][k] = bf16(W1[k][c])  [128][512];  W2pt[q][r] = bf16(W2[(k*128+r)*40+c]) [160][128]
__global__ void wprep_kernel(const float* __restrict__ W1, const float* __restrict__ W2,
                             unsigned short* __restrict__ W1t,
                             unsigned short* __restrict__ W2pt) {
  int t = blockIdx.x * blockDim.x + threadIdx.x;
  if (t < 512 * 128) {
    int c = t >> 9, k = t & 511;
    W1t[t] = f2bf(W1[(size_t)k * 128 + c]);
  } else if (t < 512 * 128 + 160 * 128) {
    int u = t - 512 * 128;
    int q = u >> 7, r = u & 127;
    int k = q / 40, c = q - k * 40;
    W2pt[u] = f2bf(W2[(size_t)(k * 128 + r) * 40 + c]);
  }
}

// ---------------- x -> bf16 into P block 0 ----------------
__global__ void copyx_kernel(const float* __restrict__ x, unsigned short* __restrict__ P, int n) {
  int t = blockIdx.x * blockDim.x + threadIdx.x;
  int i = t >> 5;
  int c4 = (t & 31) << 2;
  if (i < n) {
    float4 v = *(const float4*)&x[(size_t)i * 128 + c4];
    unsigned lo = (unsigned)f2bf(v.x) | ((unsigned)f2bf(v.y) << 16);
    unsigned hi = (unsigned)f2bf(v.z) | ((unsigned)f2bf(v.w) << 16);
    uint2 o; o.x = lo; o.y = hi;
    *(uint2*)&P[(size_t)i * 512 + c4] = o;
  }
}

// ---------------- 128-dim bf16 propagation (wave per node, shfl-broadcast CSR) ----------------
__global__ __launch_bounds__(256) void prop128b_kernel(
    const unsigned short* __restrict__ in, unsigned short* __restrict__ out,
    const int* __restrict__ row_ptr, const int2* __restrict__ csr, int n) {
  int node = (int)((blockIdx.x * blockDim.x + threadIdx.x) >> 6);
  int lane = threadIdx.x & 63;
  if (node >= n) return;
  int beg = row_ptr[node], end = row_ptr[node + 1];
  int deg = end - beg;
  // lane-distributed preload of up to 64 CSR entries
  int2 ent = make_int2(0, 0);
  if (lane < deg) ent = csr[beg + lane];
  float ax = 0.f, ay = 0.f;
  int m = deg < 64 ? deg : 64;
  int j = 0;
  for (; j + 4 <= m; j += 4) {
    int s0 = __shfl(ent.x, j, 64);
    int s1 = __shfl(ent.x, j + 1, 64);
    int s2 = __shfl(ent.x, j + 2, 64);
    int s3 = __shfl(ent.x, j + 3, 64);
    float w0 = __int_as_float(__shfl(ent.y, j, 64));
    float w1 = __int_as_float(__shfl(ent.y, j + 1, 64));
    float w2 = __int_as_float(__shfl(ent.y, j + 2, 64));
    float w3 = __int_as_float(__shfl(ent.y, j + 3, 64));
    unsigned p0 = *(const unsigned*)&in[(size_t)s0 * 512 + 2 * lane];
    unsigned p1 = *(const unsigned*)&in[(size_t)s1 * 512 + 2 * lane];
    unsigned p2 = *(const unsigned*)&in[(size_t)s2 * 512 + 2 * lane];
    unsigned p3 = *(const unsigned*)&in[(size_t)s3 * 512 + 2 * lane];
    ax = fmaf(w0, bflo(p0), ax); ay = fmaf(w0, bfhi(p0), ay);
    ax = fmaf(w1, bflo(p1), ax); ay = fmaf(w1, bfhi(p1), ay);
    ax = fmaf(w2, bflo(p2), ax); ay = fmaf(w2, bfhi(p2), ay);
    ax = fmaf(w3, bflo(p3), ax); ay = fmaf(w3, bfhi(p3), ay);
  }
  for (; j < m; ++j) {
    int s0 = __shfl(ent.x, j, 64);
    float w0 = __int_as_float(__shfl(ent.y, j, 64));
    unsigned p0 = *(const unsigned*)&in[(size_t)s0 * 512 + 2 * lane];
    ax = fmaf(w0, bflo(p0), ax); ay = fmaf(w0, bfhi(p0), ay);
  }
  // rare tail: deg > 64
  for (int t = beg + 64; t < end; ++t) {
    int2 e0 = csr[t];
    float w0 = __int_as_float(e0.y);
    unsigned p0 = *(const unsigned*)&in[(size_t)e0.x * 512 + 2 * lane];
    ax = fmaf(w0, bflo(p0), ax); ay = fmaf(w0, bfhi(p0), ay);
  }
  unsigned o = (unsigned)f2bf(ax) | ((unsigned)f2bf(ay) << 16);
  *(unsigned*)&out[(size_t)node * 512 + 2 * lane] = o;
}

// ---------------- GEMM1 (MFMA): H = relu(P[N,512] @ W1 + b1), bf16 out ----------------
__global__ __launch_bounds__(256) void gemm1m_kernel(
    const unsigned short* __restrict__ A,    // [NROWP][512] bf16
    const unsigned short* __restrict__ Bt,   // [128][512] bf16 (W1 transposed)
    const float* __restrict__ bias,
    unsigned short* __restrict__ H) {        // [NROWP][128] bf16
  __shared__ short As[64 * 32];
  __shared__ short Bs[128 * 32];
  const int tid = threadIdx.x;
  const int lane = tid & 63;
  const int w = tid >> 6;
  const int wr = w & 1;
  const int wc = w >> 1;
  const int row0 = blockIdx.x * 64;
  f32x4 acc[2][4];
#pragma unroll
  for (int i = 0; i < 2; ++i)
#pragma unroll
    for (int j = 0; j < 4; ++j) acc[i][j] = (f32x4)0.f;

  const int lrow = lane >> 2;
  const int lkp = lane & 3;

  for (int k0 = 0; k0 < 512; k0 += 32) {
    gload_lds16(A + (size_t)(row0 + w * 16 + lrow) * 512 + k0 + lkp * 8, &As[w * 512]);
    gload_lds16(Bt + (size_t)(w * 16 + lrow) * 512 + k0 + lkp * 8, &Bs[w * 512]);
    gload_lds16(Bt + (size_t)((w + 4) * 16 + lrow) * 512 + k0 + lkp * 8, &Bs[(w + 4) * 512]);
    __syncthreads();
    const int kg = lane >> 4, rr = lane & 15;
    bf16x8 af[2], bfr[4];
#pragma unroll
    for (int mr = 0; mr < 2; ++mr)
      af[mr] = __builtin_bit_cast(bf16x8,
          *(const short8v*)&As[(wr * 32 + mr * 16 + rr) * 32 + kg * 8]);
#pragma unroll
    for (int nr = 0; nr < 4; ++nr)
      bfr[nr] = __builtin_bit_cast(bf16x8,
          *(const short8v*)&Bs[(wc * 64 + nr * 16 + rr) * 32 + kg * 8]);
#pragma unroll
    for (int mr = 0; mr < 2; ++mr)
#pragma unroll
      for (int nr = 0; nr < 4; ++nr)
        acc[mr][nr] = mfma_bf16(af[mr], bfr[nr], acc[mr][nr]);
    __syncthreads();
  }
  const int cg = lane >> 4, cl = lane & 15;
#pragma unroll
  for (int mr = 0; mr < 2; ++mr)
#pragma unroll
    for (int nr = 0; nr < 4; ++nr) {
      int col = wc * 64 + nr * 16 + cl;
      float bv = bias[col];
#pragma unroll
      for (int j = 0; j < 4; ++j) {
        int row = row0 + wr * 32 + mr * 16 + cg * 4 + j;
        H[(size_t)row * 128 + col] = f2bf(fmaxf(acc[mr][nr][j] + bv, 0.f));
      }
    }
}

// ---------------- GEMM2 (MFMA): Gk[N,40] bf16, k=0..3 (compact blocks) ----------------
__global__ __launch_bounds__(256) void gemm2m_kernel(
    const unsigned short* __restrict__ A,    // [NROWP][128] bf16
    const unsigned short* __restrict__ Bt,   // [160][128] bf16
    unsigned short* __restrict__ G) {        // 4 x [NROWP][40] bf16
  __shared__ short As[64 * 32];
  __shared__ short Bs[160 * 32];
  const int tid = threadIdx.x;
  const int lane = tid & 63;
  const int w = tid >> 6;
  const int row0 = blockIdx.x * 64;
  f32x4 acc[10];
#pragma unroll
  for (int i = 0; i < 10; ++i) acc[i] = (f32x4)0.f;
  const int lrow = lane >> 2, lkp = lane & 3;

  for (int k0 = 0; k0 < 128; k0 += 32) {
    gload_lds16(A + (size_t)(row0 + w * 16 + lrow) * 128 + k0 + lkp * 8, &As[w * 512]);
    for (int c = w; c < 10; c += 4)
      gload_lds16(Bt + (size_t)(c * 16 + lrow) * 128 + k0 + lkp * 8, &Bs[c * 512]);
    __syncthreads();
    const int kg = lane >> 4, rr = lane & 15;
    bf16x8 af = __builtin_bit_cast(bf16x8,
        *(const short8v*)&As[(w * 16 + rr) * 32 + kg * 8]);
#pragma unroll
    for (int nr = 0; nr < 10; ++nr) {
      bf16x8 bfr = __builtin_bit_cast(bf16x8,
          *(const short8v*)&Bs[(nr * 16 + rr) * 32 + kg * 8]);
      acc[nr] = mfma_bf16(af, bfr, acc[nr]);
    }
    __syncthreads();
  }
  const int cg = lane >> 4, cl = lane & 15;
#pragma unroll
  for (int nr = 0; nr < 10; ++nr) {
    int col = nr * 16 + cl;      // 0..159
    int k = col / 40;            // hop block
    int o = col - k * 40;
#pragma unroll
    for (int j = 0; j < 4; ++j) {
      int row = row0 + w * 16 + cg * 4 + j;
      G[(size_t)k * NROWP * 40 + (size_t)row * 40 + o] = f2bf(acc[nr][j]);
    }
  }
}

// ---------------- 40-dim bf16 propagation with additive term (shfl CSR) ----------------
__global__ __launch_bounds__(256) void prop40b_kernel(
    const unsigned short* __restrict__ in,
    const unsigned short* __restrict__ add,
    unsigned short* __restrict__ out,
    const int* __restrict__ row_ptr, const int2* __restrict__ csr, int n) {
  int node = (int)((blockIdx.x * blockDim.x + threadIdx.x) >> 6);
  int lane = threadIdx.x & 63;
  if (node >= n) return;
  int beg = row_ptr[node], end = row_ptr[node + 1];
  int deg = end - beg;
  int2 ent = make_int2(0, 0);
  if (lane < deg) ent = csr[beg + lane];
  float acc = (lane < 40) ? bf2f(add[(size_t)node * 40 + lane]) : 0.f;
  int m = deg < 64 ? deg : 64;
  int j = 0;
  for (; j + 4 <= m; j += 4) {
    int s0 = __shfl(ent.x, j, 64);
    int s1 = __shfl(ent.x, j + 1, 64);
    int s2 = __shfl(ent.x, j + 2, 64);
    int s3 = __shfl(ent.x, j + 3, 64);
    float w0 = __int_as_float(__shfl(ent.y, j, 64));
    float w1 = __int_as_float(__shfl(ent.y, j + 1, 64));
    float w2 = __int_as_float(__shfl(ent.y, j + 2, 64));
    float w3 = __int_as_float(__shfl(ent.y, j + 3, 64));
    if (lane < 40) {
      float v0 = bf2f(in[(size_t)s0 * 40 + lane]);
      float v1 = bf2f(in[(size_t)s1 * 40 + lane]);
      float v2 = bf2f(in[(size_t)s2 * 40 + lane]);
      float v3 = bf2f(in[(size_t)s3 * 40 + lane]);
      acc = fmaf(w0, v0, acc);
      acc = fmaf(w1, v1, acc);
      acc = fmaf(w2, v2, acc);
      acc = fmaf(w3, v3, acc);
    }
  }
  for (; j < m; ++j) {
    int s0 = __shfl(ent.x, j, 64);
    float w0 = __int_as_float(__shfl(ent.y, j, 64));
    if (lane < 40) acc = fmaf(w0, bf2f(in[(size_t)s0 * 40 + lane]), acc);
  }
  for (int t = beg + 64; t < end; ++t) {
    int2 e0 = csr[t];
    if (lane < 40)
      acc = fmaf(__int_as_float(e0.y), bf2f(in[(size_t)e0.x * 40 + lane]), acc);
  }
  if (lane < 40) out[(size_t)node * 40 + lane] = f2bf(acc);
}

// ---------------- final hop fused with bias + log_softmax ----------------
__global__ __launch_bounds__(256) void prop40b_lsm_kernel(
    const unsigned short* __restrict__ in,
    const unsigned short* __restrict__ add,
    const float* __restrict__ b2,
    float* __restrict__ out,
    const int* __restrict__ row_ptr, const int2* __restrict__ csr, int n) {
  int node = (int)((blockIdx.x * blockDim.x + threadIdx.x) >> 6);
  int lane = threadIdx.x & 63;
  if (node >= n) return;
  int beg = row_ptr[node], end = row_ptr[node + 1];
  int deg = end - beg;
  int2 ent = make_int2(0, 0);
  if (lane < deg) ent = csr[beg + lane];
  float acc = (lane < 40) ? bf2f(add[(size_t)node * 40 + lane]) : 0.f;
  int m = deg < 64 ? deg : 64;
  int j = 0;
  for (; j + 4 <= m; j += 4) {
    int s0 = __shfl(ent.x, j, 64);
    int s1 = __shfl(ent.x, j + 1, 64);
    int s2 = __shfl(ent.x, j + 2, 64);
    int s3 = __shfl(ent.x, j + 3, 64);
    float w0 = __int_as_float(__shfl(ent.y, j, 64));
    float w1 = __int_as_float(__shfl(ent.y, j + 1, 64));
    float w2 = __int_as_float(__shfl(ent.y, j + 2, 64));
    float w3 = __int_as_float(__shfl(ent.y, j + 3, 64));
    if (lane < 40) {
      float v0 = bf2f(in[(size_t)s0 * 40 + lane]);
      float v1 = bf2f(in[(size_t)s1 * 40 + lane]);
      float v2 = bf2f(in[(size_t)s2 * 40 + lane]);
      float v3 = bf2f(in[(size_t)s3 * 40 + lane]);
      acc = fmaf(w0, v0, acc);
      acc = fmaf(w1, v1, acc);
      acc = fmaf(w2, v2, acc);
      acc = fmaf(w3, v3, acc);
    }
  }
  for (; j < m; ++j) {
    int s0 = __shfl(ent.x, j, 64);
    float w0 = __int_as_float(__shfl(ent.y, j, 64));
    if (lane < 40) acc = fmaf(w0, bf2f(in[(size_t)s0 * 40 + lane]), acc);
  }
  for (int t = beg + 64; t < end; ++t) {
    int2 e0 = csr[t];
    if (lane < 40)
      acc = fmaf(__int_as_float(e0.y), bf2f(in[(size_t)e0.x * 40 + lane]), acc);
  }
  float v = (lane < 40) ? acc + b2[lane] : -__builtin_inff();
  float mx = v;
#pragma unroll
  for (int o = 32; o; o >>= 1) mx = fmaxf(mx, __shfl_xor(mx, o, 64));
  float p = (lane < 40) ? expf(v - mx) : 0.f;
  float s = p;
#pragma unroll
  for (int o = 32; o; o >>= 1) s += __shfl_xor(s, o, 64);
  if (lane < 40) out[(size_t)node * 40 + lane] = v - mx - logf(s);
}

extern "C" void kernel_launch(void* const* d_in, const int* in_sizes, int n_in,
                              void* d_out, int out_size, void* d_ws, size_t ws_size,
                              hipStream_t stream) {
  const float* x  = (const float*)d_in[0];
  const int*   ei = (const int*)d_in[1];
  const float* W1 = (const float*)d_in[2];
  const float* b1 = (const float*)d_in[3];
  const float* W2 = (const float*)d_in[4];
  const float* b2 = (const float*)d_in[5];
  const int* srcv = ei;
  const int* dstv = ei + NEDGES;
  float* out = (float*)d_out;

  char* wsb = (char*)d_ws;
  size_t off = 0;
  auto alloc = [&](size_t bytes) {
    char* p = wsb + off;
    off += (bytes + 255) & ~(size_t)255;
    return p;
  };
  int*            cnt     = (int*)            alloc((size_t)NNODES * 4);
  float*          dis     = (float*)          alloc((size_t)NNODES * 4);
  int*            row_ptr = (int*)            alloc(((size_t)NNODES + 1) * 4);
  int*            bcur    = (int*)            alloc((size_t)256 * 4);
  int*            bsums   = (int*)            alloc((size_t)SCAN_NB * 4);
  int*            boff    = (int*)            alloc((size_t)SCAN_NB * 4);
  int2*           bkt     = (int2*)           alloc((size_t)NBKT * BCAP * 8);
  int2*           csr     = (int2*)           alloc((size_t)NEDGES * 8);
  unsigned short* W1t     = (unsigned short*) alloc((size_t)128 * 512 * 2);
  unsigned short* W2pt    = (unsigned short*) alloc((size_t)160 * 128 * 2);
  unsigned short* P       = (unsigned short*) alloc((size_t)NROWP * 512 * 2);
  unsigned short* H       = (unsigned short*) alloc((size_t)NROWP * 128 * 2);
  unsigned short* G       = (unsigned short*) alloc((size_t)4 * NROWP * 40 * 2);
  unsigned short* tb      = (unsigned short*) alloc((size_t)NNODES * 40 * 2);
  unsigned short* t2      = (unsigned short*) alloc((size_t)NNODES * 40 * 2);

  unsigned short* G0 = G;
  unsigned short* G1 = G + (size_t)1 * NROWP * 40;
  unsigned short* G2 = G + (size_t)2 * NROWP * 40;
  unsigned short* G3 = G + (size_t)3 * NROWP * 40;

  hipMemsetAsync(bcur, 0, 256 * 4, stream);
  bucketA_kernel<<<ABLK, 256, 0, stream>>>(srcv, dstv, bcur, bkt);
  histB_kernel<<<NBKT, 256, 0, stream>>>(bcur, bkt, cnt, NNODES);
  bsum_kernel<<<SCAN_NB, 256, 0, stream>>>(cnt, bsums, NNODES);
  bscan_kernel<<<1, 64, 0, stream>>>(bsums, boff, row_ptr, SCAN_NB, NNODES);
  bfinal_kernel<<<SCAN_NB, 256, 0, stream>>>(cnt, boff, row_ptr, dis, NNODES);
  scatB_kernel<<<NBKT, 256, 0, stream>>>(bcur, bkt, row_ptr, dis, csr, NNODES);
  wprep_kernel<<<(512 * 128 + 160 * 128 + 255) / 256, 256, 0, stream>>>(W1, W2, W1t, W2pt);
  copyx_kernel<<<((NNODES * 32) + 255) / 256, 256, 0, stream>>>(x, P, NNODES);

  const int prop_blocks = (NNODES * 64 + 255) / 256;
  // Layer 1: P blocks k = A_hat^k x  (bf16, row stride 512)
  for (int k = 1; k <= KHOP; ++k)
    prop128b_kernel<<<prop_blocks, 256, 0, stream>>>(P + 128 * (k - 1), P + 128 * k,
                                                     row_ptr, csr, NNODES);
  const int gemm_blocks = (NNODES + 63) / 64;  // 784; rows < NROWP
  gemm1m_kernel<<<gemm_blocks, 256, 0, stream>>>(P, W1t, b1, H);
  gemm2m_kernel<<<gemm_blocks, 256, 0, stream>>>(H, W2pt, G);
  // Horner (bf16 storage, fp32 accum): tb = A*G3 + G2 ; t2 = A*tb + G1 ; out = lsm(A*t2 + G0 + b2)
  prop40b_kernel<<<prop_blocks, 256, 0, stream>>>(G3, G2, tb, row_ptr, csr, NNODES);
  prop40b_kernel<<<prop_blocks, 256, 0, stream>>>(tb, G1, t2, row_ptr, csr, NNODES);
  prop40b_lsm_kernel<<<prop_blocks, 256, 0, stream>>>(t2, G0, b2, out, row_ptr, csr, NNODES);
}

// Round 7
// 254.324 us; speedup vs baseline: 2.7923x; 1.0208x over previous
//
#include <hip/hip_runtime.h>
#include <hip/hip_bf16.h>

#define NNODES 50000
#define NROWP  50176   // padded row count (multiple of 64) for GEMM tiles
#define NEDGES 800000
#define KHOP 3
#define SCAN_NB 49     // ceil(NNODES / 1024)
#define NBKT 196       // ceil(50176/256) buckets of 256 nodes
#define BCAP 6144      // entries per bucket (mean 4082, sd ~64 -> safe)
#define ABLK 400       // pass-A blocks
#define ACH  2000      // edges per pass-A block

typedef __attribute__((ext_vector_type(8))) short short8v;
typedef __attribute__((ext_vector_type(8))) __bf16 bf16x8;
typedef __attribute__((ext_vector_type(4))) float f32x4;

__device__ inline unsigned short f2bf(float f) {
  unsigned u = __builtin_bit_cast(unsigned, f);
  u += 0x7fffu + ((u >> 16) & 1u);   // RNE
  return (unsigned short)(u >> 16);
}
__device__ inline float bf2f(unsigned short h) {
  return __builtin_bit_cast(float, (unsigned)h << 16);
}
__device__ inline float bflo(unsigned u) { return __builtin_bit_cast(float, u << 16); }
__device__ inline float bfhi(unsigned u) { return __builtin_bit_cast(float, u & 0xffff0000u); }

__device__ inline void gload_lds16(const void* g, void* l) {
  __builtin_amdgcn_global_load_lds(
      (const __attribute__((address_space(1))) unsigned int*)g,
      (__attribute__((address_space(3))) unsigned int*)l, 16, 0, 0);
}

__device__ inline f32x4 mfma_bf16(bf16x8 a, bf16x8 b, f32x4 c) {
  return __builtin_amdgcn_mfma_f32_16x16x32_bf16(a, b, c, 0, 0, 0);
}

__device__ inline void fma8(float* acc, float w, short8v v) {
  uint4 u = __builtin_bit_cast(uint4, v);
  acc[0] = fmaf(w, bflo(u.x), acc[0]);
  acc[1] = fmaf(w, bfhi(u.x), acc[1]);
  acc[2] = fmaf(w, bflo(u.y), acc[2]);
  acc[3] = fmaf(w, bfhi(u.y), acc[3]);
  acc[4] = fmaf(w, bflo(u.z), acc[4]);
  acc[5] = fmaf(w, bfhi(u.z), acc[5]);
  acc[6] = fmaf(w, bflo(u.w), acc[6]);
  acc[7] = fmaf(w, bfhi(u.w), acc[7]);
}

__device__ inline void fma4(float* acc, float w, uint2 v) {
  acc[0] = fmaf(w, bflo(v.x), acc[0]);
  acc[1] = fmaf(w, bfhi(v.x), acc[1]);
  acc[2] = fmaf(w, bflo(v.y), acc[2]);
  acc[3] = fmaf(w, bfhi(v.y), acc[3]);
}

// ---------------- Pass A: bucket edges by dst>>8 ----------------
__global__ __launch_bounds__(256) void bucketA_kernel(
    const int* __restrict__ src, const int* __restrict__ dst,
    int* __restrict__ bcur, int2* __restrict__ bkt) {
  __shared__ int2 eb[ACH];
  __shared__ int hist[256];
  __shared__ int base[256];
  int tid = threadIdx.x;
  int e0 = blockIdx.x * ACH;
  int cnt = NEDGES - e0; if (cnt > ACH) cnt = ACH;
  hist[tid] = 0;
  __syncthreads();
  for (int i = tid; i < cnt; i += 256) {
    int s = src[e0 + i], d = dst[e0 + i];
    eb[i] = make_int2(s, d);
    atomicAdd(&hist[d >> 8], 1);
  }
  __syncthreads();
  base[tid] = atomicAdd(&bcur[tid], hist[tid]);
  hist[tid] = 0;
  __syncthreads();
  for (int i = tid; i < cnt; i += 256) {
    int2 e = eb[i];
    int b = e.y >> 8;
    int off = atomicAdd(&hist[b], 1);
    bkt[(size_t)b * BCAP + base[b] + off] = e;
  }
}

// ---------------- per-bucket node histogram ----------------
__global__ __launch_bounds__(256) void histB_kernel(
    const int* __restrict__ bcur, const int2* __restrict__ bkt,
    int* __restrict__ cnt, int n) {
  __shared__ int h[256];
  int b = blockIdx.x, tid = threadIdx.x;
  h[tid] = 0;
  __syncthreads();
  int sz = bcur[b];
  for (int i = tid; i < sz; i += 256)
    atomicAdd(&h[bkt[(size_t)b * BCAP + i].y & 255], 1);
  __syncthreads();
  int node = b * 256 + tid;
  if (node < n) cnt[node] = h[tid];
}

// --- hierarchical exclusive scan: bsum -> bscan -> bfinal (+dis fused) ---
__global__ __launch_bounds__(256) void bsum_kernel(const int* __restrict__ cnt,
                                                   int* __restrict__ bsums, int n) {
  __shared__ int sd[256];
  int tid = threadIdx.x;
  int base = blockIdx.x * 1024 + tid * 4;
  int s = 0;
  if (base + 4 <= n) {
    int4 v = *(const int4*)&cnt[base];
    s = v.x + v.y + v.z + v.w;
  }
  sd[tid] = s;
  __syncthreads();
  for (int o = 128; o; o >>= 1) {
    if (tid < o) sd[tid] += sd[tid + o];
    __syncthreads();
  }
  if (tid == 0) bsums[blockIdx.x] = sd[0];
}

__global__ __launch_bounds__(64) void bscan_kernel(const int* __restrict__ bsums,
                                                   int* __restrict__ boff,
                                                   int* __restrict__ row_ptr,
                                                   int nb, int n) {
  int tid = threadIdx.x;
  int own = (tid < nb) ? bsums[tid] : 0;
  int v = own;
#pragma unroll
  for (int o = 1; o < 64; o <<= 1) {
    int t = __shfl_up(v, o, 64);
    if (tid >= o) v += t;
  }
  if (tid < nb) boff[tid] = v - own;   // exclusive block offset
  if (tid == 63) row_ptr[n] = v;       // total edge count
}

__global__ __launch_bounds__(256) void bfinal_kernel(const int* __restrict__ cnt,
                                                     const int* __restrict__ boff,
                                                     int* __restrict__ row_ptr,
                                                     float* __restrict__ dis, int n) {
  __shared__ int sd[256];
  int tid = threadIdx.x;
  int base = blockIdx.x * 1024 + tid * 4;
  int4 v = make_int4(0, 0, 0, 0);
  bool ok = (base + 4 <= n);
  if (ok) v = *(const int4*)&cnt[base];
  int s = v.x + v.y + v.z + v.w;
  sd[tid] = s;
  __syncthreads();
  for (int o = 1; o < 256; o <<= 1) {
    int t = (tid >= o) ? sd[tid - o] : 0;
    __syncthreads();
    sd[tid] += t;
    __syncthreads();
  }
  if (ok) {
    int run = boff[blockIdx.x] + sd[tid] - s;  // exclusive prefix
    int4 rp;
    rp.x = run;
    rp.y = run + v.x;
    rp.z = rp.y + v.y;
    rp.w = rp.z + v.z;
    *(int4*)&row_ptr[base] = rp;
    float4 dv;
    dv.x = (v.x > 0) ? rsqrtf((float)v.x) : 0.f;
    dv.y = (v.y > 0) ? rsqrtf((float)v.y) : 0.f;
    dv.z = (v.z > 0) ? rsqrtf((float)v.z) : 0.f;
    dv.w = (v.w > 0) ? rsqrtf((float)v.w) : 0.f;
    *(float4*)&dis[base] = dv;
  }
}

// ---------------- Pass B: per-bucket scatter into CSR ----------------
__global__ __launch_bounds__(256) void scatB_kernel(
    const int* __restrict__ bcur, const int2* __restrict__ bkt,
    const int* __restrict__ row_ptr, const float* __restrict__ dis,
    int2* __restrict__ csr, int n) {
  __shared__ int cur[256];
  int b = blockIdx.x, tid = threadIdx.x;
  int node = b * 256 + tid;
  cur[tid] = (node < n) ? row_ptr[node] : 0;
  __syncthreads();
  int sz = bcur[b];
  for (int i = tid; i < sz; i += 256) {
    int2 e = bkt[(size_t)b * BCAP + i];
    int pos = atomicAdd(&cur[e.y & 255], 1);
    int2 ent;
    ent.x = e.x;
    ent.y = __float_as_int(dis[e.x] * dis[e.y]);
    csr[pos] = ent;
  }
}

// ---------------- fused weight transforms ----------------
__global__ void wprep_kernel(const float* __restrict__ W1, const float* __restrict__ W2,
                             unsigned short* __restrict__ W1t,
                             unsigned short* __restrict__ W2pt) {
  int t = blockIdx.x * blockDim.x + threadIdx.x;
  if (t < 512 * 128) {
    int c = t >> 9, k = t & 511;
    W1t[t] = f2bf(W1[(size_t)k * 128 + c]);
  } else if (t < 512 * 128 + 160 * 128) {
    int u = t - 512 * 128;
    int q = u >> 7, r = u & 127;
    int k = q / 40, c = q - k * 40;
    W2pt[u] = f2bf(W2[(size_t)(k * 128 + r) * 40 + c]);
  }
}

// ---------------- x -> bf16 into P block 0 ----------------
__global__ void copyx_kernel(const float* __restrict__ x, unsigned short* __restrict__ P, int n) {
  int t = blockIdx.x * blockDim.x + threadIdx.x;
  int i = t >> 5;
  int c4 = (t & 31) << 2;
  if (i < n) {
    float4 v = *(const float4*)&x[(size_t)i * 128 + c4];
    unsigned lo = (unsigned)f2bf(v.x) | ((unsigned)f2bf(v.y) << 16);
    unsigned hi = (unsigned)f2bf(v.z) | ((unsigned)f2bf(v.w) << 16);
    uint2 o; o.x = lo; o.y = hi;
    *(uint2*)&P[(size_t)i * 512 + c4] = o;
  }
}

// ---------------- 128-dim bf16 propagation: 4 edge-slots x 16 lanes, 16B loads ----------------
__global__ __launch_bounds__(256) void prop128c_kernel(
    const unsigned short* __restrict__ in, unsigned short* __restrict__ out,
    const int* __restrict__ row_ptr, const int2* __restrict__ csr, int n) {
  int node = (int)((blockIdx.x * blockDim.x + threadIdx.x) >> 6);
  int lane = threadIdx.x & 63;
  if (node >= n) return;
  int beg = row_ptr[node], end = row_ptr[node + 1];
  int deg = end - beg;
  int2 ent = make_int2(0, 0);
  if (lane < deg) ent = csr[beg + lane];
  const int grp = lane >> 4, sub = lane & 15;
  float acc[8] = {0.f, 0.f, 0.f, 0.f, 0.f, 0.f, 0.f, 0.f};
  int m = deg < 64 ? deg : 64;
  for (int j = 0; j < m; j += 4) {
    int idx = j + grp;
    bool act = idx < m;
    int ic = act ? idx : m - 1;
    int s = __shfl(ent.x, ic, 64);
    float w = __int_as_float(__shfl(ent.y, ic, 64));
    if (!act) w = 0.f;
    short8v v = *(const short8v*)(in + (size_t)s * 512 + sub * 8);
    fma8(acc, w, v);
  }
  // rare tail: deg > 64 (slot 0 only contributes)
  for (int t = beg + 64; t < end; ++t) {
    int2 e0 = csr[t];
    float w = (grp == 0) ? __int_as_float(e0.y) : 0.f;
    short8v v = *(const short8v*)(in + (size_t)e0.x * 512 + sub * 8);
    fma8(acc, w, v);
  }
#pragma unroll
  for (int i = 0; i < 8; ++i) {
    acc[i] += __shfl_xor(acc[i], 16, 64);
    acc[i] += __shfl_xor(acc[i], 32, 64);
  }
  if (grp == 0) {
    uint4 r;
    r.x = (unsigned)f2bf(acc[0]) | ((unsigned)f2bf(acc[1]) << 16);
    r.y = (unsigned)f2bf(acc[2]) | ((unsigned)f2bf(acc[3]) << 16);
    r.z = (unsigned)f2bf(acc[4]) | ((unsigned)f2bf(acc[5]) << 16);
    r.w = (unsigned)f2bf(acc[6]) | ((unsigned)f2bf(acc[7]) << 16);
    *(uint4*)(out + (size_t)node * 512 + sub * 8) = r;
  }
}

// ---------------- GEMM1 (MFMA): H = relu(P[N,512] @ W1 + b1), bf16 out ----------------
__global__ __launch_bounds__(256) void gemm1m_kernel(
    const unsigned short* __restrict__ A,    // [NROWP][512] bf16
    const unsigned short* __restrict__ Bt,   // [128][512] bf16 (W1 transposed)
    const float* __restrict__ bias,
    unsigned short* __restrict__ H) {        // [NROWP][128] bf16
  __shared__ short As[64 * 32];
  __shared__ short Bs[128 * 32];
  const int tid = threadIdx.x;
  const int lane = tid & 63;
  const int w = tid >> 6;
  const int wr = w & 1;
  const int wc = w >> 1;
  const int row0 = blockIdx.x * 64;
  f32x4 acc[2][4];
#pragma unroll
  for (int i = 0; i < 2; ++i)
#pragma unroll
    for (int j = 0; j < 4; ++j) acc[i][j] = (f32x4)0.f;

  const int lrow = lane >> 2;
  const int lkp = lane & 3;

  for (int k0 = 0; k0 < 512; k0 += 32) {
    gload_lds16(A + (size_t)(row0 + w * 16 + lrow) * 512 + k0 + lkp * 8, &As[w * 512]);
    gload_lds16(Bt + (size_t)(w * 16 + lrow) * 512 + k0 + lkp * 8, &Bs[w * 512]);
    gload_lds16(Bt + (size_t)((w + 4) * 16 + lrow) * 512 + k0 + lkp * 8, &Bs[(w + 4) * 512]);
    __syncthreads();
    const int kg = lane >> 4, rr = lane & 15;
    bf16x8 af[2], bfr[4];
#pragma unroll
    for (int mr = 0; mr < 2; ++mr)
      af[mr] = __builtin_bit_cast(bf16x8,
          *(const short8v*)&As[(wr * 32 + mr * 16 + rr) * 32 + kg * 8]);
#pragma unroll
    for (int nr = 0; nr < 4; ++nr)
      bfr[nr] = __builtin_bit_cast(bf16x8,
          *(const short8v*)&Bs[(wc * 64 + nr * 16 + rr) * 32 + kg * 8]);
#pragma unroll
    for (int mr = 0; mr < 2; ++mr)
#pragma unroll
      for (int nr = 0; nr < 4; ++nr)
        acc[mr][nr] = mfma_bf16(af[mr], bfr[nr], acc[mr][nr]);
    __syncthreads();
  }
  const int cg = lane >> 4, cl = lane & 15;
#pragma unroll
  for (int mr = 0; mr < 2; ++mr)
#pragma unroll
    for (int nr = 0; nr < 4; ++nr) {
      int col = wc * 64 + nr * 16 + cl;
      float bv = bias[col];
#pragma unroll
      for (int j = 0; j < 4; ++j) {
        int row = row0 + wr * 32 + mr * 16 + cg * 4 + j;
        H[(size_t)row * 128 + col] = f2bf(fmaxf(acc[mr][nr][j] + bv, 0.f));
      }
    }
}

// ---------------- GEMM2 (MFMA): Gk[N,64-padded] bf16, k=0..3 ----------------
__global__ __launch_bounds__(256) void gemm2m_kernel(
    const unsigned short* __restrict__ A,    // [NROWP][128] bf16
    const unsigned short* __restrict__ Bt,   // [160][128] bf16
    unsigned short* __restrict__ G) {        // 4 x [NROWP][64] bf16 (cols 40..63 pad)
  __shared__ short As[64 * 32];
  __shared__ short Bs[160 * 32];
  const int tid = threadIdx.x;
  const int lane = tid & 63;
  const int w = tid >> 6;
  const int row0 = blockIdx.x * 64;
  f32x4 acc[10];
#pragma unroll
  for (int i = 0; i < 10; ++i) acc[i] = (f32x4)0.f;
  const int lrow = lane >> 2, lkp = lane & 3;

  for (int k0 = 0; k0 < 128; k0 += 32) {
    gload_lds16(A + (size_t)(row0 + w * 16 + lrow) * 128 + k0 + lkp * 8, &As[w * 512]);
    for (int c = w; c < 10; c += 4)
      gload_lds16(Bt + (size_t)(c * 16 + lrow) * 128 + k0 + lkp * 8, &Bs[c * 512]);
    __syncthreads();
    const int kg = lane >> 4, rr = lane & 15;
    bf16x8 af = __builtin_bit_cast(bf16x8,
        *(const short8v*)&As[(w * 16 + rr) * 32 + kg * 8]);
#pragma unroll
    for (int nr = 0; nr < 10; ++nr) {
      bf16x8 bfr = __builtin_bit_cast(bf16x8,
          *(const short8v*)&Bs[(nr * 16 + rr) * 32 + kg * 8]);
      acc[nr] = mfma_bf16(af, bfr, acc[nr]);
    }
    __syncthreads();
  }
  const int cg = lane >> 4, cl = lane & 15;
#pragma unroll
  for (int nr = 0; nr < 10; ++nr) {
    int col = nr * 16 + cl;      // 0..159
    int k = col / 40;            // hop block
    int o = col - k * 40;
#pragma unroll
    for (int j = 0; j < 4; ++j) {
      int row = row0 + w * 16 + cg * 4 + j;
      G[(size_t)k * NROWP * 64 + (size_t)row * 64 + o] = f2bf(acc[nr][j]);
    }
  }
}

// ---------------- 40(64-pad)-dim propagation: 4 slots x 16 lanes, 8B loads ----------------
__global__ __launch_bounds__(256) void prop40c_kernel(
    const unsigned short* __restrict__ in,   // [n][64] bf16 (pad cols garbage-ok)
    const unsigned short* __restrict__ add,  // [n][64]
    unsigned short* __restrict__ out,        // [n][64]
    const int* __restrict__ row_ptr, const int2* __restrict__ csr, int n) {
  int node = (int)((blockIdx.x * blockDim.x + threadIdx.x) >> 6);
  int lane = threadIdx.x & 63;
  if (node >= n) return;
  int beg = row_ptr[node], end = row_ptr[node + 1];
  int deg = end - beg;
  int2 ent = make_int2(0, 0);
  if (lane < deg) ent = csr[beg + lane];
  const int grp = lane >> 4, sub = lane & 15;
  float acc[4] = {0.f, 0.f, 0.f, 0.f};
  if (grp == 0) {
    uint2 a = *(const uint2*)(add + (size_t)node * 64 + sub * 4);
    acc[0] = bflo(a.x); acc[1] = bfhi(a.x);
    acc[2] = bflo(a.y); acc[3] = bfhi(a.y);
  }
  int m = deg < 64 ? deg : 64;
  for (int j = 0; j < m; j += 4) {
    int idx = j + grp;
    bool act = idx < m;
    int ic = act ? idx : m - 1;
    int s = __shfl(ent.x, ic, 64);
    float w = __int_as_float(__shfl(ent.y, ic, 64));
    if (!act) w = 0.f;
    uint2 v = *(const uint2*)(in + (size_t)s * 64 + sub * 4);
    fma4(acc, w, v);
  }
  for (int t = beg + 64; t < end; ++t) {
    int2 e0 = csr[t];
    float w = (grp == 0) ? __int_as_float(e0.y) : 0.f;
    uint2 v = *(const uint2*)(in + (size_t)e0.x * 64 + sub * 4);
    fma4(acc, w, v);
  }
#pragma unroll
  for (int i = 0; i < 4; ++i) {
    acc[i] += __shfl_xor(acc[i], 16, 64);
    acc[i] += __shfl_xor(acc[i], 32, 64);
  }
  if (grp == 0) {
    uint2 r;
    r.x = (unsigned)f2bf(acc[0]) | ((unsigned)f2bf(acc[1]) << 16);
    r.y = (unsigned)f2bf(acc[2]) | ((unsigned)f2bf(acc[3]) << 16);
    *(uint2*)(out + (size_t)node * 64 + sub * 4) = r;
  }
}

// ---------------- final hop fused with bias + log_softmax ----------------
__global__ __launch_bounds__(256) void prop40c_lsm_kernel(
    const unsigned short* __restrict__ in,   // [n][64]
    const unsigned short* __restrict__ add,  // [n][64]
    const float* __restrict__ b2,
    float* __restrict__ out,                 // [n][40] f32
    const int* __restrict__ row_ptr, const int2* __restrict__ csr, int n) {
  int node = (int)((blockIdx.x * blockDim.x + threadIdx.x) >> 6);
  int lane = threadIdx.x & 63;
  if (node >= n) return;
  int beg = row_ptr[node], end = row_ptr[node + 1];
  int deg = end - beg;
  int2 ent = make_int2(0, 0);
  if (lane < deg) ent = csr[beg + lane];
  const int grp = lane >> 4, sub = lane & 15;
  float acc[4] = {0.f, 0.f, 0.f, 0.f};
  if (grp == 0) {
    uint2 a = *(const uint2*)(add + (size_t)node * 64 + sub * 4);
    acc[0] = bflo(a.x); acc[1] = bfhi(a.x);
    acc[2] = bflo(a.y); acc[3] = bfhi(a.y);
  }
  int m = deg < 64 ? deg : 64;
  for (int j = 0; j < m; j += 4) {
    int idx = j + grp;
    bool act = idx < m;
    int ic = act ? idx : m - 1;
    int s = __shfl(ent.x, ic, 64);
    float w = __int_as_float(__shfl(ent.y, ic, 64));
    if (!act) w = 0.f;
    uint2 v = *(const uint2*)(in + (size_t)s * 64 + sub * 4);
    fma4(acc, w, v);
  }
  for (int t = beg + 64; t < end; ++t) {
    int2 e0 = csr[t];
    float w = (grp == 0) ? __int_as_float(e0.y) : 0.f;
    uint2 v = *(const uint2*)(in + (size_t)e0.x * 64 + sub * 4);
    fma4(acc, w, v);
  }
#pragma unroll
  for (int i = 0; i < 4; ++i) {
    acc[i] += __shfl_xor(acc[i], 16, 64);
    acc[i] += __shfl_xor(acc[i], 32, 64);
  }
  // every lane now holds the full sums for cols sub*4..sub*4+3
  bool val = (sub < 10);
  float vv[4];
  if (val) {
    float4 bv = *(const float4*)(b2 + sub * 4);
    vv[0] = acc[0] + bv.x; vv[1] = acc[1] + bv.y;
    vv[2] = acc[2] + bv.z; vv[3] = acc[3] + bv.w;
  } else {
    vv[0] = vv[1] = vv[2] = vv[3] = -__builtin_inff();
  }
  float mx = fmaxf(fmaxf(vv[0], vv[1]), fmaxf(vv[2], vv[3]));
#pragma unroll
  for (int o = 1; o < 16; o <<= 1) mx = fmaxf(mx, __shfl_xor(mx, o, 64));
  float s = 0.f;
  if (val)
    s = expf(vv[0] - mx) + expf(vv[1] - mx) + expf(vv[2] - mx) + expf(vv[3] - mx);
#pragma unroll
  for (int o = 1; o < 16; o <<= 1) s += __shfl_xor(s, o, 64);
  if (val) {
    float ls = logf(s);
    float4 o4;
    o4.x = vv[0] - mx - ls; o4.y = vv[1] - mx - ls;
    o4.z = vv[2] - mx - ls; o4.w = vv[3] - mx - ls;
    *(float4*)(out + (size_t)node * 40 + sub * 4) = o4;
  }
}

extern "C" void kernel_launch(void* const* d_in, const int* in_sizes, int n_in,
                              void* d_out, int out_size, void* d_ws, size_t ws_size,
                              hipStream_t stream) {
  const float* x  = (const float*)d_in[0];
  const int*   ei = (const int*)d_in[1];
  const float* W1 = (const float*)d_in[2];
  const float* b1 = (const float*)d_in[3];
  const float* W2 = (const float*)d_in[4];
  const float* b2 = (const float*)d_in[5];
  const int* srcv = ei;
  const int* dstv = ei + NEDGES;
  float* out = (float*)d_out;

  char* wsb = (char*)d_ws;
  size_t off = 0;
  auto alloc = [&](size_t bytes) {
    char* p = wsb + off;
    off += (bytes + 255) & ~(size_t)255;
    return p;
  };
  int*            cnt     = (int*)            alloc((size_t)NNODES * 4);
  float*          dis     = (float*)          alloc((size_t)NNODES * 4);
  int*            row_ptr = (int*)            alloc(((size_t)NNODES + 1) * 4);
  int*            bcur    = (int*)            alloc((size_t)256 * 4);
  int*            bsums   = (int*)            alloc((size_t)SCAN_NB * 4);
  int*            boff    = (int*)            alloc((size_t)SCAN_NB * 4);
  int2*           bkt     = (int2*)           alloc((size_t)NBKT * BCAP * 8);
  int2*           csr     = (int2*)           alloc((size_t)NEDGES * 8);
  unsigned short* W1t     = (unsigned short*) alloc((size_t)128 * 512 * 2);
  unsigned short* W2pt    = (unsigned short*) alloc((size_t)160 * 128 * 2);
  unsigned short* P       = (unsigned short*) alloc((size_t)NROWP * 512 * 2);
  unsigned short* H       = (unsigned short*) alloc((size_t)NROWP * 128 * 2);
  unsigned short* G       = (unsigned short*) alloc((size_t)4 * NROWP * 64 * 2);
  unsigned short* tb      = (unsigned short*) alloc((size_t)NNODES * 64 * 2);
  unsigned short* t2      = (unsigned short*) alloc((size_t)NNODES * 64 * 2);

  unsigned short* G0 = G;
  unsigned short* G1 = G + (size_t)1 * NROWP * 64;
  unsigned short* G2 = G + (size_t)2 * NROWP * 64;
  unsigned short* G3 = G + (size_t)3 * NROWP * 64;

  hipMemsetAsync(bcur, 0, 256 * 4, stream);
  bucketA_kernel<<<ABLK, 256, 0, stream>>>(srcv, dstv, bcur, bkt);
  histB_kernel<<<NBKT, 256, 0, stream>>>(bcur, bkt, cnt, NNODES);
  bsum_kernel<<<SCAN_NB, 256, 0, stream>>>(cnt, bsums, NNODES);
  bscan_kernel<<<1, 64, 0, stream>>>(bsums, boff, row_ptr, SCAN_NB, NNODES);
  bfinal_kernel<<<SCAN_NB, 256, 0, stream>>>(cnt, boff, row_ptr, dis, NNODES);
  scatB_kernel<<<NBKT, 256, 0, stream>>>(bcur, bkt, row_ptr, dis, csr, NNODES);
  wprep_kernel<<<(512 * 128 + 160 * 128 + 255) / 256, 256, 0, stream>>>(W1, W2, W1t, W2pt);
  copyx_kernel<<<((NNODES * 32) + 255) / 256, 256, 0, stream>>>(x, P, NNODES);

  const int prop_blocks = (NNODES * 64 + 255) / 256;
  // Layer 1: P blocks k = A_hat^k x  (bf16, row stride 512)
  for (int k = 1; k <= KHOP; ++k)
    prop128c_kernel<<<prop_blocks, 256, 0, stream>>>(P + 128 * (k - 1), P + 128 * k,
                                                     row_ptr, csr, NNODES);
  const int gemm_blocks = (NNODES + 63) / 64;  // 784; rows < NROWP
  gemm1m_kernel<<<gemm_blocks, 256, 0, stream>>>(P, W1t, b1, H);
  gemm2m_kernel<<<gemm_blocks, 256, 0, stream>>>(H, W2pt, G);
  // Horner (bf16 storage, fp32 accum): tb = A*G3 + G2 ; t2 = A*tb + G1 ; out = lsm(A*t2 + G0 + b2)
  prop40c_kernel<<<prop_blocks, 256, 0, stream>>>(G3, G2, tb, row_ptr, csr, NNODES);
  prop40c_kernel<<<prop_blocks, 256, 0, stream>>>(tb, G1, t2, row_ptr, csr, NNODES);
  prop40c_lsm_kernel<<<prop_blocks, 256, 0, stream>>>(t2, G0, b2, out, row_ptr, csr, NNODES);
}